// Round 19
// baseline (462.710 us; speedup 1.0000x reference)
//
#include <hip/hip_runtime.h>

#define DEV __device__ __forceinline__

typedef short  bf16x8 __attribute__((ext_vector_type(8)));
typedef float  f32x4  __attribute__((ext_vector_type(4)));

DEV unsigned short f2b(float f) {
    unsigned int u = __float_as_uint(f);
    u += 0x7fffu + ((u >> 16) & 1u);
    return (unsigned short)(u >> 16);
}
DEV float b2f(unsigned short h) { return __uint_as_float((unsigned int)h << 16); }
DEV float silu(float x) { return x / (1.f + __expf(-x)); }
DEV float fexp2(float x) { return __builtin_amdgcn_exp2f(x); }   // raw v_exp_f32
DEV float flog2(float x) { return __builtin_amdgcn_logf(x); }    // raw v_log_f32

// async global->LDS, 16B per lane: HW writes lane l at ldsbase + l*16
typedef const __attribute__((address_space(1))) unsigned int GU32;
typedef __attribute__((address_space(3))) unsigned int LU32;
DEV void gload16(const unsigned short* g, unsigned short* l) {
    __builtin_amdgcn_global_load_lds((GU32*)g, (LU32*)l, 16, 0, 0);
}

// ---------------------------------------------------------------------------
// f32 -> bf16 elementwise convert (n multiple of 4)
__global__ __launch_bounds__(256) void k_cvt(const float* __restrict__ s,
                                             unsigned short* __restrict__ d, int n) {
    int i = (blockIdx.x * 256 + threadIdx.x) * 4;
    if (i + 3 < n) {
        float4 v = *(const float4*)(s + i);
        ushort4 o;
        o.x = f2b(v.x); o.y = f2b(v.y); o.z = f2b(v.z); o.w = f2b(v.w);
        *(ushort4*)(d + i) = o;
    }
}

// up_w (512 x 512 x 4) [i,o,k] -> upT[(k*512+o)*512 + i] bf16
__global__ void k_upT(const float* __restrict__ up_w, unsigned short* __restrict__ upT) {
    __shared__ float t[32][33];
    int tx = threadIdx.x, ty = threadIdx.y;
    int o0 = blockIdx.x * 32, i0 = blockIdx.y * 32, kz = blockIdx.z;
    t[ty][tx] = up_w[(size_t)(i0 + ty) * 2048 + (o0 + tx) * 4 + kz];
    __syncthreads();
    upT[(size_t)(kz * 512 + o0 + ty) * 512 + i0 + tx] = f2b(t[tx][ty]);
}

// dt packing: split-bf16 exact GEMM operands (K=32 -> K=128).
// A: dtraw = xdbl[:, 0:32] -> Ap[m][0:32]=xh, [32:64]=xl, [64:96]=xh, [96:128]=xl
__global__ __launch_bounds__(256) void k_dtpackA(const float* __restrict__ xdbl,
                                                 unsigned short* __restrict__ Ap) {
    int i = blockIdx.x * 256 + threadIdx.x;   // (m, r), r fastest
    int m = i >> 5, r = i & 31;
    float x = xdbl[(size_t)m * 64 + r];
    unsigned short xh = f2b(x);
    unsigned short xl = f2b(x - b2f(xh));
    size_t base = (size_t)m * 128;
    Ap[base + r]      = xh;
    Ap[base + 32 + r] = xl;
    Ap[base + 64 + r] = xh;
    Ap[base + 96 + r] = xl;
}

// B: dt_proj_w (1024 x 32) -> Bp[d][0:32]=wh, [32:64]=wl, [64:96]=wl, [96:128]=wh
// sum over K=128: xh*wh + xl*wl + xh*wl + xl*wh = (xh+xl)*(wh+wl)  (exact split)
__global__ __launch_bounds__(256) void k_dtpackB(const float* __restrict__ w,
                                                 unsigned short* __restrict__ Bp) {
    int i = blockIdx.x * 256 + threadIdx.x;   // (d, r)
    int d = i >> 5, r = i & 31;
    float x = w[(size_t)d * 32 + r];
    unsigned short wh = f2b(x);
    unsigned short wl = f2b(x - b2f(wh));
    size_t base = (size_t)d * 128;
    Bp[base + r]      = wh;
    Bp[base + 32 + r] = wl;
    Bp[base + 64 + r] = wl;
    Bp[base + 96 + r] = wh;
}

// ---------------------------------------------------------------------------
// bf16 MFMA GEMM, NT: C[m,n] = sum_k A[m,k]*B[n,k].  BK=32, 4 waves,
// m97-style global_load_lds staging (linear LDS, 16B/lane).
// XCD-aware block swizzle (T1): contiguous tile chunks per XCD for L2 reuse.
// Tiles: (BM,BN) in {(128,128),(128,64),(64,64)}.
// OUTMODE 0: f32 out, 1: bf16 out, 2: softplus -> f32, 3: softplus -> bf16.
template <int BM, int BN, int OUTMODE>
__global__ __launch_bounds__(256) void k_gemm(const unsigned short* __restrict__ A,
                                              const unsigned short* __restrict__ B,
                                              float* __restrict__ Cf,
                                              unsigned short* __restrict__ Cb,
                                              const float* __restrict__ bias,
                                              int M, int N, int K) {
    constexpr int BK = 32;
    constexpr int WM = (BN == 128) ? 64 : 32;
    constexpr int WN = (BM == 64 && BN == 64) ? 32 : 64;
    constexpr int MI = WM / 16, NI = WN / 16;
    __shared__ unsigned short As[BM * BK];
    __shared__ unsigned short Bs[BN * BK];
    const int tid = threadIdx.x;
    const int wid = tid >> 6, lane = tid & 63;

    // XCD swizzle: hw bids round-robin XCDs; map same-XCD bids to contiguous tiles
    int bid = blockIdx.y * gridDim.x + blockIdx.x;
    const int nwg = gridDim.x * gridDim.y;
    if ((nwg & 7) == 0) {
        int cpx = nwg >> 3;
        bid = (bid & 7) * cpx + (bid >> 3);
    }
    const int bx = bid % gridDim.x, by = bid / gridDim.x;
    const int m0 = by * BM, n0 = bx * BN;

    int wr, wc;
    if (BN == 128)      { wr = wid >> 1; wc = wid & 1; }
    else if (BM == 128) { wr = wid;      wc = 0;       }
    else                { wr = wid & 1;  wc = wid >> 1; }
    const int wm0 = wr * WM, wn0 = wc * WN;
    const int fr = lane & 15, fh = lane >> 4;

    // staging geometry: wave w stages 16-row strips; lane l -> row w*16+(l>>2),
    // col (l&3)*8 ushorts; LDS dest is wave-uniform strip base (linear layout).
    const int srow = wid * 16 + (lane >> 2);
    const int scol = (lane & 3) * 8;
    const unsigned short* Ag = A + (size_t)(m0 + srow) * K + scol;
    const unsigned short* Bg = B + (size_t)(n0 + srow) * K + scol;
    unsigned short* AsB = &As[wid * 16 * BK];
    unsigned short* BsB = &Bs[wid * 16 * BK];

    f32x4 acc[MI][NI];
#pragma unroll
    for (int i = 0; i < MI; ++i)
#pragma unroll
        for (int j = 0; j < NI; ++j) acc[i][j] = (f32x4){0.f, 0.f, 0.f, 0.f};

    for (int k0 = 0; k0 < K; k0 += BK) {
        gload16(Ag + k0, AsB);
        if (BM == 128) gload16(Ag + (size_t)64 * K + k0, AsB + 64 * BK);
        gload16(Bg + k0, BsB);
        if (BN == 128) gload16(Bg + (size_t)64 * K + k0, BsB + 64 * BK);
        __syncthreads();
        bf16x8 av[MI], bv[NI];
#pragma unroll
        for (int mi = 0; mi < MI; ++mi)
            av[mi] = *(const bf16x8*)(&As[(wm0 + mi * 16 + fr) * BK + fh * 8]);
#pragma unroll
        for (int ni = 0; ni < NI; ++ni)
            bv[ni] = *(const bf16x8*)(&Bs[(wn0 + ni * 16 + fr) * BK + fh * 8]);
#pragma unroll
        for (int mi = 0; mi < MI; ++mi)
#pragma unroll
            for (int ni = 0; ni < NI; ++ni)
                acc[mi][ni] = __builtin_amdgcn_mfma_f32_16x16x32_bf16(av[mi], bv[ni],
                                                                      acc[mi][ni], 0, 0, 0);
        __syncthreads();
    }
    constexpr float LOG2E = 1.4426950408889634f;
    constexpr float LN2   = 0.6931471805599453f;
#pragma unroll
    for (int mi = 0; mi < MI; ++mi) {
#pragma unroll
        for (int ni = 0; ni < NI; ++ni) {
            int col = n0 + wn0 + ni * 16 + fr;
            float bb = bias ? bias[col] : 0.f;
#pragma unroll
            for (int j = 0; j < 4; ++j) {
                int row = m0 + wm0 + mi * 16 + fh * 4 + j;
                float v = acc[mi][ni][j] + bb;
                if (OUTMODE == 0)      Cf[(size_t)row * N + col] = v;
                else if (OUTMODE == 1) Cb[(size_t)row * N + col] = f2b(v);
                else {
                    float sp = (v > 20.f) ? v : flog2(1.f + fexp2(v * LOG2E)) * LN2;
                    if (OUTMODE == 2) Cf[(size_t)row * N + col] = sp;
                    else              Cb[(size_t)row * N + col] = f2b(sp);
                }
            }
        }
    }
}

// ---------------------------------------------------------------------------
// assemble cat row-major (8192 x 1024) bf16: [0,512)=xu from P, [512,1024)=skip
__global__ __launch_bounds__(256) void k_assemble(const float* __restrict__ P,
                                                  const float* __restrict__ skip,
                                                  const float* __restrict__ up_b,
                                                  unsigned short* __restrict__ catbf) {
    int bx = blockIdx.x;
    int m = bx >> 2;
    int c = (bx & 3) * 256 + threadIdx.x;
    int b = m >> 10, t = m & 1023, j = t >> 1;
    float v;
    if (c < 512) {
        size_t rb = (size_t)((b << 9) + j) * 2048;
        if (t & 1) {                       // odd t: k=2 @ j, k=0 @ j+1
            v = P[rb + 1024 + c];
            if (j + 1 < 512) v += P[rb + 2048 + c];
        } else {                           // even t: k=3 @ j-1, k=1 @ j
            v = P[rb + 512 + c];
            if (j >= 1) v += P[rb - 2048 + 1536 + c];
        }
        v += up_b[c];
    } else {
        v = skip[(size_t)m * 512 + (c - 512)];
    }
    catbf[(size_t)m * 1024 + c] = f2b(v);
}

// LayerNorm over 512, 4 rows per 256-block, writes bf16
__global__ __launch_bounds__(256) void k_ln(const float* __restrict__ merged,
                                            const float* __restrict__ w,
                                            const float* __restrict__ bvec,
                                            unsigned short* __restrict__ outb) {
    int row = blockIdx.x * 4 + (threadIdx.x >> 6);
    int lane = threadIdx.x & 63;
    const float* r = merged + (size_t)row * 512 + lane * 8;
    float4 v1 = *(const float4*)r;
    float4 v2 = *(const float4*)(r + 4);
    float xv[8] = {v1.x, v1.y, v1.z, v1.w, v2.x, v2.y, v2.z, v2.w};
    float s = 0.f, ss = 0.f;
#pragma unroll
    for (int e = 0; e < 8; ++e) { s += xv[e]; ss += xv[e] * xv[e]; }
#pragma unroll
    for (int m = 1; m < 64; m <<= 1) { s += __shfl_xor(s, m, 64); ss += __shfl_xor(ss, m, 64); }
    float mean = s * (1.f / 512.f);
    float var = ss * (1.f / 512.f) - mean * mean;
    float inv = rsqrtf(var + 1e-5f);
    unsigned short o8[8];
#pragma unroll
    for (int e = 0; e < 8; ++e) {
        int c = lane * 8 + e;
        o8[e] = f2b((xv[e] - mean) * inv * w[c] + bvec[c]);
    }
    *(int4*)(outb + (size_t)row * 512 + lane * 8) = *(const int4*)o8;
}

// causal depthwise conv K=4 + bias + silu; 4 channels/thread, bf16 in/out
__global__ __launch_bounds__(256) void k_conv(const unsigned short* __restrict__ xzb,
                                              const float* __restrict__ cw,
                                              const float* __restrict__ cb,
                                              unsigned short* __restrict__ xcb) {
    int i = blockIdx.x * 256 + threadIdx.x;   // 2.1M threads
    int m = i >> 8;
    int c0 = (i & 255) * 4;
    int l = m & 1023;
    float4 w0 = *(const float4*)(cw + (size_t)(c0 + 0) * 4);
    float4 w1 = *(const float4*)(cw + (size_t)(c0 + 1) * 4);
    float4 w2 = *(const float4*)(cw + (size_t)(c0 + 2) * 4);
    float4 w3 = *(const float4*)(cw + (size_t)(c0 + 3) * 4);
    float4 acc = *(const float4*)(cb + c0);
    const float* wp0 = (const float*)&w0;
    const float* wp1 = (const float*)&w1;
    const float* wp2 = (const float*)&w2;
    const float* wp3 = (const float*)&w3;
#pragma unroll
    for (int k = 0; k < 4; ++k) {
        int lp = l - 3 + k;
        if (lp >= 0) {
            ushort4 xv = *(const ushort4*)(xzb + (size_t)(m - l + lp) * 2048 + c0);
            acc.x = fmaf(wp0[k], b2f(xv.x), acc.x);
            acc.y = fmaf(wp1[k], b2f(xv.y), acc.y);
            acc.z = fmaf(wp2[k], b2f(xv.z), acc.z);
            acc.w = fmaf(wp3[k], b2f(xv.w), acc.w);
        }
    }
    ushort4 o = { f2b(silu(acc.x)), f2b(silu(acc.y)), f2b(silu(acc.z)), f2b(silu(acc.w)) };
    *(ushort4*)(xcb + (size_t)m * 1024 + c0) = o;
}

// ---------------------------------------------------------------------------
// Chunked selective scan.  L=1024 split into NC=32 chunks of CL=32.
// Thread = (b, d, chunk), 16 states in registers.  dt/u staged in LDS
// (bulk coalesced prefetch per chunk -> no per-step global latency).
// PHASE 0: from h=0, store (exp2(A2*dtsum), h_final) per chunk -> ap, hf.
// PHASE 1: read h_init (in hf after carry), compute y, fused D*u + silu(z).
// Power fast path: A[s]=(s+1)*A[0] -> a_s = a1^(s+1) (guarded, exact fallback).
// Block = 256 threads = 256 consecutive d; grid (4 dgrp, 8 b, NC chunk).
constexpr int SCAN_NC = 32;
constexpr int SCAN_CL = 32;

template <int PHASE>
__global__ __launch_bounds__(256) void k_scan_chunk(
        const unsigned short* __restrict__ dtb, const unsigned short* __restrict__ xcb,
        const float* __restrict__ xdbl, const unsigned short* __restrict__ xzb,
        const float* __restrict__ Alog, const float* __restrict__ Dp,
        float* __restrict__ ap, float* __restrict__ hf,
        unsigned short* __restrict__ ybf) {
    constexpr int CL = SCAN_CL;
    const int tid = threadIdx.x;
    const int d0 = blockIdx.x * 256;
    const int d = d0 + tid;
    const int b = blockIdx.y, c = blockIdx.z;
    const size_t mbase = (size_t)b * 1024 + (size_t)c * CL;

    // bulk-stage chunk inputs into LDS (coalesced 16B chunks, all in flight):
    //   sBC: B/C slice of xdbl; sdt/su: this block's dt/u [CL][256] bf16.
    __shared__ float sBC[CL][32];
    __shared__ unsigned short sdt[CL][256];
    __shared__ unsigned short su[CL][256];
    {
        int row = tid >> 3, q = tid & 7;   // CL*8 == 256
        *(float4*)&sBC[row][q * 4] =
            *(const float4*)(xdbl + (mbase + row) * 64 + 32 + q * 4);
    }
    for (int i = tid; i < CL * 32; i += 256) {       // 32 rows x 32 16B-chunks
        int row = i >> 5, q = i & 31;
        const size_t g = (mbase + row) * 1024 + d0 + q * 8;
        *(int4*)&sdt[row][q * 8] = *(const int4*)(dtb + g);
        *(int4*)&su[row][q * 8]  = *(const int4*)(xcb + g);
    }
    __syncthreads();

    constexpr float LOG2E = 1.4426950408889634f;
    float A2[16], h[16];
#pragma unroll
    for (int s = 0; s < 16; ++s) A2[s] = -expf(Alog[d * 16 + s]) * LOG2E;

    // integer-ratio check: A2[s] == (s+1)*A2[0] to ~1e-5 rel
    bool powok = true;
#pragma unroll
    for (int s = 1; s < 16; ++s)
        powok = powok && (fabsf(A2[s] - (float)(s + 1) * A2[0]) <=
                          1e-5f * fabsf(A2[s]));

    const size_t sumbase = ((size_t)(b * SCAN_NC + c) << 14) + d * 16;
    if (PHASE == 0) {
#pragma unroll
        for (int s = 0; s < 16; ++s) h[s] = 0.f;
    } else {
#pragma unroll
        for (int s = 0; s < 16; s += 4)
            *(f32x4*)&h[s] = *(const f32x4*)(hf + sumbase + s);
    }
    float dtsum = 0.f;
    const float Dv = (PHASE == 1) ? Dp[d] : 0.f;

    // z prefetch one step ahead (phase 1 only)
    float zv_n = 0.f;
    if (PHASE == 1) zv_n = b2f(xzb[mbase * 2048 + 1024 + d]);

#pragma unroll 2
    for (int l = 0; l < CL; ++l) {
        const size_t m = mbase + l;
        const float dtv_c = b2f(sdt[l][tid]);
        const float uv_c  = b2f(su[l][tid]);
        float zv;
        if (PHASE == 1) {
            zv = zv_n;
            if (l + 1 < CL) zv_n = b2f(xzb[(m + 1) * 2048 + 1024 + d]);
        }
        const float dtu = dtv_c * uv_c;
        if (PHASE == 0) dtsum += dtv_c;
        float Bv[16], Cv[16];
#pragma unroll
        for (int q = 0; q < 4; ++q) {
            *(float4*)&Bv[q * 4] = *(const float4*)&sBC[l][q * 4];
            if (PHASE == 1)
                *(float4*)&Cv[q * 4] = *(const float4*)&sBC[l][16 + q * 4];
        }
        float p = 0.f;
        if (powok) {
            const float a1 = fexp2(dtv_c * A2[0]);
            float a = a1;
#pragma unroll
            for (int s = 0; s < 16; ++s) {
                h[s] = fmaf(a, h[s], dtu * Bv[s]);
                if (PHASE == 1) p = fmaf(h[s], Cv[s], p);
                a *= a1;
            }
        } else {
#pragma unroll
            for (int s = 0; s < 16; ++s) {
                float a = fexp2(dtv_c * A2[s]);
                h[s] = fmaf(a, h[s], dtu * Bv[s]);
                if (PHASE == 1) p = fmaf(h[s], Cv[s], p);
            }
        }
        if (PHASE == 1) {
            ybf[m * 1024 + d] = f2b((p + Dv * uv_c) * silu(zv));
        }
    }
    if (PHASE == 0) {
        float aprod[16];
        if (powok) {
            const float ap1 = fexp2(A2[0] * dtsum);
            float a = ap1;
#pragma unroll
            for (int s = 0; s < 16; ++s) { aprod[s] = a; a *= ap1; }
        } else {
#pragma unroll
            for (int s = 0; s < 16; ++s) aprod[s] = fexp2(A2[s] * dtsum);
        }
#pragma unroll
        for (int s = 0; s < 16; s += 4) {
            *(f32x4*)(ap + sumbase + s) = *(const f32x4*)&aprod[s];
            *(f32x4*)(hf + sumbase + s) = *(const f32x4*)&h[s];
        }
    }
}

// carry scan over chunk summaries; rewrites hf[c] with h_init for chunk c.
__global__ __launch_bounds__(256) void k_scan_carry(const float* __restrict__ ap,
                                                    float* __restrict__ hf) {
    int i = blockIdx.x * 256 + threadIdx.x;   // (b, d*16+s)
    int b = i >> 14, ds = i & 16383;
    float h = 0.f;
    for (int c = 0; c < SCAN_NC; ++c) {
        size_t idx = ((size_t)(b * SCAN_NC + c) << 14) + ds;
        float a = ap[idx], f = hf[idx];
        hf[idx] = h;
        h = fmaf(a, h, f);
    }
}

// ---------------------------------------------------------------------------
extern "C" void kernel_launch(void* const* d_in, const int* in_sizes, int n_in,
                              void* d_out, int out_size, void* d_ws, size_t ws_size,
                              hipStream_t stream) {
    const float* x         = (const float*)d_in[0];
    const float* skip      = (const float*)d_in[1];
    const float* up_w      = (const float*)d_in[2];
    const float* up_b      = (const float*)d_in[3];
    const float* merge_w   = (const float*)d_in[4];
    const float* merge_b   = (const float*)d_in[5];
    const float* ln_w      = (const float*)d_in[6];
    const float* ln_b      = (const float*)d_in[7];
    const float* in_proj_w = (const float*)d_in[8];
    const float* conv_w    = (const float*)d_in[9];
    const float* conv_b    = (const float*)d_in[10];
    const float* x_proj_w  = (const float*)d_in[11];
    const float* dt_proj_w = (const float*)d_in[12];
    const float* dt_proj_b = (const float*)d_in[13];
    const float* A_log     = (const float*)d_in[14];
    const float* D_param   = (const float*)d_in[15];
    const float* out_proj_w= (const float*)d_in[16];
    float* out = (float*)d_out;

    char* ws = (char*)d_ws;
    size_t off = 0;
    auto alloc = [&](size_t bytes) { size_t r = off; off += (bytes + 255) & ~(size_t)255; return r; };

    // persistent
    unsigned short* upT  = (unsigned short*)(ws + alloc(2048ull * 512 * 2));
    unsigned short* mw   = (unsigned short*)(ws + alloc(512ull * 1024 * 2));
    unsigned short* ipw  = (unsigned short*)(ws + alloc(2ull * 2048 * 512 * 2));
    unsigned short* xpw  = (unsigned short*)(ws + alloc(2ull * 64 * 1024 * 2));
    unsigned short* opw  = (unsigned short*)(ws + alloc(2ull * 512 * 1024 * 2));
    unsigned short* xbf  = (unsigned short*)(ws + alloc(4096ull * 512 * 2));
    unsigned short* ubf  = (unsigned short*)(ws + alloc(8192ull * 512 * 2));
    // per-layer arena (stage-1 buffers aliased in)
    unsigned short* xzbf  = (unsigned short*)(ws + alloc(8192ull * 2048 * 2));
    unsigned short* xcbf  = (unsigned short*)(ws + alloc(8192ull * 1024 * 2));
    float*          xdbl  = (float*)(ws + alloc(8192ull * 64 * 4));
    unsigned short* dtbf  = (unsigned short*)(ws + alloc(8192ull * 1024 * 2));
    unsigned short* ybf   = (unsigned short*)(ws + alloc(8192ull * 1024 * 2));
    float*          scan_ap = (float*)(ws + alloc((size_t)SCAN_NC * 8 * 16384 * 4));
    float*          scan_hf = (float*)(ws + alloc((size_t)SCAN_NC * 8 * 16384 * 4));
    unsigned short* dtpA  = (unsigned short*)(ws + alloc(8192ull * 128 * 2));
    unsigned short* dtpB  = (unsigned short*)(ws + alloc(1024ull * 128 * 2));
    float*          P      = (float*)xzbf;          // 32MB == 32MB, dead before in_proj
    unsigned short* catbf  = dtbf;                  // 16MB == 16MB, dead before dt GEMM
    float*          merged = (float*)xcbf;          // 16MB == 16MB, dead before conv

    // weight/activation conversions
    k_cvt<<<2048, 256, 0, stream>>>(x, xbf, 4096 * 512);
    k_cvt<<<512, 256, 0, stream>>>(merge_w, mw, 512 * 1024);
    k_cvt<<<2048, 256, 0, stream>>>(in_proj_w, ipw, 2 * 2048 * 512);
    k_cvt<<<128, 256, 0, stream>>>(x_proj_w, xpw, 2 * 64 * 1024);
    k_cvt<<<1024, 256, 0, stream>>>(out_proj_w, opw, 2 * 512 * 1024);
    k_upT<<<dim3(16, 16, 4), dim3(32, 32), 0, stream>>>(up_w, upT);

    // stage 1: transposed-conv as GEMM, assemble cat, merge GEMM, LN
    k_gemm<128, 128, 0><<<dim3(16, 32), 256, 0, stream>>>(xbf, upT, P, nullptr, nullptr,
                                                          4096, 2048, 512);
    k_assemble<<<32768, 256, 0, stream>>>(P, skip, up_b, catbf);
    k_gemm<128, 128, 0><<<dim3(4, 64), 256, 0, stream>>>(catbf, mw, merged, nullptr, merge_b,
                                                         8192, 512, 1024);
    k_ln<<<2048, 256, 0, stream>>>(merged, ln_w, ln_b, ubf);

    // two mamba layers
    for (int li = 0; li < 2; ++li) {
        k_gemm<128, 128, 1><<<dim3(16, 64), 256, 0, stream>>>(ubf, ipw + (size_t)li * 2048 * 512,
                                                              nullptr, xzbf, nullptr, 8192, 2048, 512);
        k_conv<<<8192, 256, 0, stream>>>(xzbf, conv_w + li * 4096, conv_b + li * 1024, xcbf);
        k_gemm<64, 64, 0><<<dim3(1, 128), 256, 0, stream>>>(xcbf, xpw + (size_t)li * 64 * 1024,
                                                            xdbl, nullptr, nullptr, 8192, 64, 1024);
        // dt path: exact split-bf16 GEMM (K=128) + fused hw-softplus -> bf16
        k_dtpackA<<<1024, 256, 0, stream>>>(xdbl, dtpA);
        k_dtpackB<<<128, 256, 0, stream>>>(dt_proj_w + (size_t)li * 32768, dtpB);
        k_gemm<128, 64, 3><<<dim3(16, 64), 256, 0, stream>>>(dtpA, dtpB, nullptr, dtbf,
                                                             dt_proj_b + (size_t)li * 1024,
                                                             8192, 1024, 128);
        const float* Al = A_log + (size_t)li * 1024 * 16;
        const float* Dl = D_param + (size_t)li * 1024;
        k_scan_chunk<0><<<dim3(4, 8, SCAN_NC), 256, 0, stream>>>(
            dtbf, xcbf, xdbl, xzbf, Al, Dl, scan_ap, scan_hf, ybf);
        k_scan_carry<<<512, 256, 0, stream>>>(scan_ap, scan_hf);
        k_scan_chunk<1><<<dim3(4, 8, SCAN_NC), 256, 0, stream>>>(
            dtbf, xcbf, xdbl, xzbf, Al, Dl, scan_ap, scan_hf, ybf);
        if (li == 0)
            k_gemm<128, 128, 1><<<dim3(4, 64), 256, 0, stream>>>(ybf, opw, nullptr, ubf, nullptr,
                                                                 8192, 512, 1024);
        else
            k_gemm<128, 128, 0><<<dim3(4, 64), 256, 0, stream>>>(ybf, opw + (size_t)512 * 1024,
                                                                 out, nullptr, nullptr, 8192, 512, 1024);
    }
}

// Round 20
// 452.671 us; speedup vs baseline: 1.0222x; 1.0222x over previous
//
#include <hip/hip_runtime.h>

#define DEV __device__ __forceinline__

typedef short  bf16x8 __attribute__((ext_vector_type(8)));
typedef float  f32x4  __attribute__((ext_vector_type(4)));

DEV unsigned short f2b(float f) {
    unsigned int u = __float_as_uint(f);
    u += 0x7fffu + ((u >> 16) & 1u);
    return (unsigned short)(u >> 16);
}
DEV float b2f(unsigned short h) { return __uint_as_float((unsigned int)h << 16); }
DEV float silu(float x) { return x / (1.f + __expf(-x)); }
DEV float fexp2(float x) { return __builtin_amdgcn_exp2f(x); }   // raw v_exp_f32
DEV float flog2(float x) { return __builtin_amdgcn_logf(x); }    // raw v_log_f32

// async global->LDS, 16B per lane: HW writes lane l at ldsbase + l*16
typedef const __attribute__((address_space(1))) unsigned int GU32;
typedef __attribute__((address_space(3))) unsigned int LU32;
DEV void gload16(const unsigned short* g, unsigned short* l) {
    __builtin_amdgcn_global_load_lds((GU32*)g, (LU32*)l, 16, 0, 0);
}

// ---------------------------------------------------------------------------
// f32 -> bf16 elementwise convert (n multiple of 4)
__global__ __launch_bounds__(256) void k_cvt(const float* __restrict__ s,
                                             unsigned short* __restrict__ d, int n) {
    int i = (blockIdx.x * 256 + threadIdx.x) * 4;
    if (i + 3 < n) {
        float4 v = *(const float4*)(s + i);
        ushort4 o;
        o.x = f2b(v.x); o.y = f2b(v.y); o.z = f2b(v.z); o.w = f2b(v.w);
        *(ushort4*)(d + i) = o;
    }
}

// up_w (512 x 512 x 4) [i,o,k] -> upT[(k*512+o)*512 + i] bf16
__global__ void k_upT(const float* __restrict__ up_w, unsigned short* __restrict__ upT) {
    __shared__ float t[32][33];
    int tx = threadIdx.x, ty = threadIdx.y;
    int o0 = blockIdx.x * 32, i0 = blockIdx.y * 32, kz = blockIdx.z;
    t[ty][tx] = up_w[(size_t)(i0 + ty) * 2048 + (o0 + tx) * 4 + kz];
    __syncthreads();
    upT[(size_t)(kz * 512 + o0 + ty) * 512 + i0 + tx] = f2b(t[tx][ty]);
}

// dt packing: split-bf16 exact GEMM operands (K=32 -> K=128).
// A: dtraw = xdbl[:, 0:32] -> Ap[m][0:32]=xh, [32:64]=xl, [64:96]=xh, [96:128]=xl
__global__ __launch_bounds__(256) void k_dtpackA(const float* __restrict__ xdbl,
                                                 unsigned short* __restrict__ Ap) {
    int i = blockIdx.x * 256 + threadIdx.x;   // (m, r), r fastest
    int m = i >> 5, r = i & 31;
    float x = xdbl[(size_t)m * 64 + r];
    unsigned short xh = f2b(x);
    unsigned short xl = f2b(x - b2f(xh));
    size_t base = (size_t)m * 128;
    Ap[base + r]      = xh;
    Ap[base + 32 + r] = xl;
    Ap[base + 64 + r] = xh;
    Ap[base + 96 + r] = xl;
}

// B: dt_proj_w (1024 x 32) -> Bp[d][0:32]=wh, [32:64]=wl, [64:96]=wl, [96:128]=wh
// sum over K=128: xh*wh + xl*wl + xh*wl + xl*wh = (xh+xl)*(wh+wl)  (exact split)
__global__ __launch_bounds__(256) void k_dtpackB(const float* __restrict__ w,
                                                 unsigned short* __restrict__ Bp) {
    int i = blockIdx.x * 256 + threadIdx.x;   // (d, r)
    int d = i >> 5, r = i & 31;
    float x = w[(size_t)d * 32 + r];
    unsigned short wh = f2b(x);
    unsigned short wl = f2b(x - b2f(wh));
    size_t base = (size_t)d * 128;
    Bp[base + r]      = wh;
    Bp[base + 32 + r] = wl;
    Bp[base + 64 + r] = wl;
    Bp[base + 96 + r] = wh;
}

// ---------------------------------------------------------------------------
// bf16 MFMA GEMM, NT: C[m,n] = sum_k A[m,k]*B[n,k].  BK=32, 4 waves,
// m97-style global_load_lds staging (linear LDS, 16B/lane).
// XCD-aware block swizzle (T1): contiguous tile chunks per XCD for L2 reuse.
// Tiles: (BM,BN) in {(128,128),(128,64),(64,64)}.
// OUTMODE 0: f32 out, 1: bf16 out, 2: softplus -> f32, 3: softplus -> bf16.
template <int BM, int BN, int OUTMODE>
__global__ __launch_bounds__(256) void k_gemm(const unsigned short* __restrict__ A,
                                              const unsigned short* __restrict__ B,
                                              float* __restrict__ Cf,
                                              unsigned short* __restrict__ Cb,
                                              const float* __restrict__ bias,
                                              int M, int N, int K) {
    constexpr int BK = 32;
    constexpr int WM = (BN == 128) ? 64 : 32;
    constexpr int WN = (BM == 64 && BN == 64) ? 32 : 64;
    constexpr int MI = WM / 16, NI = WN / 16;
    __shared__ unsigned short As[BM * BK];
    __shared__ unsigned short Bs[BN * BK];
    const int tid = threadIdx.x;
    const int wid = tid >> 6, lane = tid & 63;

    // XCD swizzle: hw bids round-robin XCDs; map same-XCD bids to contiguous tiles
    int bid = blockIdx.y * gridDim.x + blockIdx.x;
    const int nwg = gridDim.x * gridDim.y;
    if ((nwg & 7) == 0) {
        int cpx = nwg >> 3;
        bid = (bid & 7) * cpx + (bid >> 3);
    }
    const int bx = bid % gridDim.x, by = bid / gridDim.x;
    const int m0 = by * BM, n0 = bx * BN;

    int wr, wc;
    if (BN == 128)      { wr = wid >> 1; wc = wid & 1; }
    else if (BM == 128) { wr = wid;      wc = 0;       }
    else                { wr = wid & 1;  wc = wid >> 1; }
    const int wm0 = wr * WM, wn0 = wc * WN;
    const int fr = lane & 15, fh = lane >> 4;

    // staging geometry: wave w stages 16-row strips; lane l -> row w*16+(l>>2),
    // col (l&3)*8 ushorts; LDS dest is wave-uniform strip base (linear layout).
    const int srow = wid * 16 + (lane >> 2);
    const int scol = (lane & 3) * 8;
    const unsigned short* Ag = A + (size_t)(m0 + srow) * K + scol;
    const unsigned short* Bg = B + (size_t)(n0 + srow) * K + scol;
    unsigned short* AsB = &As[wid * 16 * BK];
    unsigned short* BsB = &Bs[wid * 16 * BK];

    f32x4 acc[MI][NI];
#pragma unroll
    for (int i = 0; i < MI; ++i)
#pragma unroll
        for (int j = 0; j < NI; ++j) acc[i][j] = (f32x4){0.f, 0.f, 0.f, 0.f};

    for (int k0 = 0; k0 < K; k0 += BK) {
        gload16(Ag + k0, AsB);
        if (BM == 128) gload16(Ag + (size_t)64 * K + k0, AsB + 64 * BK);
        gload16(Bg + k0, BsB);
        if (BN == 128) gload16(Bg + (size_t)64 * K + k0, BsB + 64 * BK);
        __syncthreads();
        bf16x8 av[MI], bv[NI];
#pragma unroll
        for (int mi = 0; mi < MI; ++mi)
            av[mi] = *(const bf16x8*)(&As[(wm0 + mi * 16 + fr) * BK + fh * 8]);
#pragma unroll
        for (int ni = 0; ni < NI; ++ni)
            bv[ni] = *(const bf16x8*)(&Bs[(wn0 + ni * 16 + fr) * BK + fh * 8]);
#pragma unroll
        for (int mi = 0; mi < MI; ++mi)
#pragma unroll
            for (int ni = 0; ni < NI; ++ni)
                acc[mi][ni] = __builtin_amdgcn_mfma_f32_16x16x32_bf16(av[mi], bv[ni],
                                                                      acc[mi][ni], 0, 0, 0);
        __syncthreads();
    }
    constexpr float LOG2E = 1.4426950408889634f;
    constexpr float LN2   = 0.6931471805599453f;
#pragma unroll
    for (int mi = 0; mi < MI; ++mi) {
#pragma unroll
        for (int ni = 0; ni < NI; ++ni) {
            int col = n0 + wn0 + ni * 16 + fr;
            float bb = bias ? bias[col] : 0.f;
#pragma unroll
            for (int j = 0; j < 4; ++j) {
                int row = m0 + wm0 + mi * 16 + fh * 4 + j;
                float v = acc[mi][ni][j] + bb;
                if (OUTMODE == 0)      Cf[(size_t)row * N + col] = v;
                else if (OUTMODE == 1) Cb[(size_t)row * N + col] = f2b(v);
                else {
                    float sp = (v > 20.f) ? v : flog2(1.f + fexp2(v * LOG2E)) * LN2;
                    if (OUTMODE == 2) Cf[(size_t)row * N + col] = sp;
                    else              Cb[(size_t)row * N + col] = f2b(sp);
                }
            }
        }
    }
}

// ---------------------------------------------------------------------------
// assemble cat row-major (8192 x 1024) bf16: [0,512)=xu from P, [512,1024)=skip
__global__ __launch_bounds__(256) void k_assemble(const float* __restrict__ P,
                                                  const float* __restrict__ skip,
                                                  const float* __restrict__ up_b,
                                                  unsigned short* __restrict__ catbf) {
    int bx = blockIdx.x;
    int m = bx >> 2;
    int c = (bx & 3) * 256 + threadIdx.x;
    int b = m >> 10, t = m & 1023, j = t >> 1;
    float v;
    if (c < 512) {
        size_t rb = (size_t)((b << 9) + j) * 2048;
        if (t & 1) {                       // odd t: k=2 @ j, k=0 @ j+1
            v = P[rb + 1024 + c];
            if (j + 1 < 512) v += P[rb + 2048 + c];
        } else {                           // even t: k=3 @ j-1, k=1 @ j
            v = P[rb + 512 + c];
            if (j >= 1) v += P[rb - 2048 + 1536 + c];
        }
        v += up_b[c];
    } else {
        v = skip[(size_t)m * 512 + (c - 512)];
    }
    catbf[(size_t)m * 1024 + c] = f2b(v);
}

// LayerNorm over 512, 4 rows per 256-block, writes bf16
__global__ __launch_bounds__(256) void k_ln(const float* __restrict__ merged,
                                            const float* __restrict__ w,
                                            const float* __restrict__ bvec,
                                            unsigned short* __restrict__ outb) {
    int row = blockIdx.x * 4 + (threadIdx.x >> 6);
    int lane = threadIdx.x & 63;
    const float* r = merged + (size_t)row * 512 + lane * 8;
    float4 v1 = *(const float4*)r;
    float4 v2 = *(const float4*)(r + 4);
    float xv[8] = {v1.x, v1.y, v1.z, v1.w, v2.x, v2.y, v2.z, v2.w};
    float s = 0.f, ss = 0.f;
#pragma unroll
    for (int e = 0; e < 8; ++e) { s += xv[e]; ss += xv[e] * xv[e]; }
#pragma unroll
    for (int m = 1; m < 64; m <<= 1) { s += __shfl_xor(s, m, 64); ss += __shfl_xor(ss, m, 64); }
    float mean = s * (1.f / 512.f);
    float var = ss * (1.f / 512.f) - mean * mean;
    float inv = rsqrtf(var + 1e-5f);
    unsigned short o8[8];
#pragma unroll
    for (int e = 0; e < 8; ++e) {
        int c = lane * 8 + e;
        o8[e] = f2b((xv[e] - mean) * inv * w[c] + bvec[c]);
    }
    *(int4*)(outb + (size_t)row * 512 + lane * 8) = *(const int4*)o8;
}

// causal depthwise conv K=4 + bias + silu; 4 channels/thread, bf16 in/out
__global__ __launch_bounds__(256) void k_conv(const unsigned short* __restrict__ xzb,
                                              const float* __restrict__ cw,
                                              const float* __restrict__ cb,
                                              unsigned short* __restrict__ xcb) {
    int i = blockIdx.x * 256 + threadIdx.x;   // 2.1M threads
    int m = i >> 8;
    int c0 = (i & 255) * 4;
    int l = m & 1023;
    float4 w0 = *(const float4*)(cw + (size_t)(c0 + 0) * 4);
    float4 w1 = *(const float4*)(cw + (size_t)(c0 + 1) * 4);
    float4 w2 = *(const float4*)(cw + (size_t)(c0 + 2) * 4);
    float4 w3 = *(const float4*)(cw + (size_t)(c0 + 3) * 4);
    float4 acc = *(const float4*)(cb + c0);
    const float* wp0 = (const float*)&w0;
    const float* wp1 = (const float*)&w1;
    const float* wp2 = (const float*)&w2;
    const float* wp3 = (const float*)&w3;
#pragma unroll
    for (int k = 0; k < 4; ++k) {
        int lp = l - 3 + k;
        if (lp >= 0) {
            ushort4 xv = *(const ushort4*)(xzb + (size_t)(m - l + lp) * 2048 + c0);
            acc.x = fmaf(wp0[k], b2f(xv.x), acc.x);
            acc.y = fmaf(wp1[k], b2f(xv.y), acc.y);
            acc.z = fmaf(wp2[k], b2f(xv.z), acc.z);
            acc.w = fmaf(wp3[k], b2f(xv.w), acc.w);
        }
    }
    ushort4 o = { f2b(silu(acc.x)), f2b(silu(acc.y)), f2b(silu(acc.z)), f2b(silu(acc.w)) };
    *(ushort4*)(xcb + (size_t)m * 1024 + c0) = o;
}

// ---------------------------------------------------------------------------
// Chunked selective scan.  L=1024 split into NC=32 chunks of CL=32.
// Thread = (b, d, chunk), 16 states in registers.  dt/u staged in LDS.
// Summaries COMPRESSED: phase0 stores packed uint32 (bf16 a | bf16 h << 16);
// carry writes compact bf16 h_init; phase1 reads bf16 h_init.
// Power fast path: A[s]=(s+1)*A[0] -> a_s = a1^(s+1) (guarded, exact fallback).
// Block = 256 threads = 256 consecutive d; grid (4 dgrp, 8 b, NC chunk).
constexpr int SCAN_NC = 32;
constexpr int SCAN_CL = 32;

template <int PHASE>
__global__ __launch_bounds__(256) void k_scan_chunk(
        const unsigned short* __restrict__ dtb, const unsigned short* __restrict__ xcb,
        const float* __restrict__ xdbl, const unsigned short* __restrict__ xzb,
        const float* __restrict__ Alog, const float* __restrict__ Dp,
        unsigned int* __restrict__ sum, const unsigned short* __restrict__ hinit,
        unsigned short* __restrict__ ybf) {
    constexpr int CL = SCAN_CL;
    const int tid = threadIdx.x;
    const int d0 = blockIdx.x * 256;
    const int d = d0 + tid;
    const int b = blockIdx.y, c = blockIdx.z;
    const size_t mbase = (size_t)b * 1024 + (size_t)c * CL;

    // bulk-stage chunk inputs into LDS (coalesced 16B chunks, all in flight):
    //   sBC: B/C slice of xdbl; sdt/su: this block's dt/u [CL][256] bf16.
    __shared__ float sBC[CL][32];
    __shared__ unsigned short sdt[CL][256];
    __shared__ unsigned short su[CL][256];
    {
        int row = tid >> 3, q = tid & 7;   // CL*8 == 256
        *(float4*)&sBC[row][q * 4] =
            *(const float4*)(xdbl + (mbase + row) * 64 + 32 + q * 4);
    }
    for (int i = tid; i < CL * 32; i += 256) {       // 32 rows x 32 16B-chunks
        int row = i >> 5, q = i & 31;
        const size_t g = (mbase + row) * 1024 + d0 + q * 8;
        *(int4*)&sdt[row][q * 8] = *(const int4*)(dtb + g);
        *(int4*)&su[row][q * 8]  = *(const int4*)(xcb + g);
    }
    __syncthreads();

    constexpr float LOG2E = 1.4426950408889634f;
    float A2[16], h[16];
#pragma unroll
    for (int s = 0; s < 16; ++s) A2[s] = -expf(Alog[d * 16 + s]) * LOG2E;

    // integer-ratio check: A2[s] == (s+1)*A2[0] to ~1e-5 rel
    bool powok = true;
#pragma unroll
    for (int s = 1; s < 16; ++s)
        powok = powok && (fabsf(A2[s] - (float)(s + 1) * A2[0]) <=
                          1e-5f * fabsf(A2[s]));

    const size_t sumbase = ((size_t)(b * SCAN_NC + c) << 14) + d * 16;
    if (PHASE == 0) {
#pragma unroll
        for (int s = 0; s < 16; ++s) h[s] = 0.f;
    } else {
#pragma unroll
        for (int s = 0; s < 16; s += 8) {
            bf16x8 hv = *(const bf16x8*)(hinit + sumbase + s);
#pragma unroll
            for (int j = 0; j < 8; ++j) h[s + j] = b2f((unsigned short)hv[j]);
        }
    }
    float dtsum = 0.f;
    const float Dv = (PHASE == 1) ? Dp[d] : 0.f;

    // z prefetch one step ahead (phase 1 only)
    float zv_n = 0.f;
    if (PHASE == 1) zv_n = b2f(xzb[mbase * 2048 + 1024 + d]);

#pragma unroll 2
    for (int l = 0; l < CL; ++l) {
        const size_t m = mbase + l;
        const float dtv_c = b2f(sdt[l][tid]);
        const float uv_c  = b2f(su[l][tid]);
        float zv;
        if (PHASE == 1) {
            zv = zv_n;
            if (l + 1 < CL) zv_n = b2f(xzb[(m + 1) * 2048 + 1024 + d]);
        }
        const float dtu = dtv_c * uv_c;
        if (PHASE == 0) dtsum += dtv_c;
        float Bv[16], Cv[16];
#pragma unroll
        for (int q = 0; q < 4; ++q) {
            *(float4*)&Bv[q * 4] = *(const float4*)&sBC[l][q * 4];
            if (PHASE == 1)
                *(float4*)&Cv[q * 4] = *(const float4*)&sBC[l][16 + q * 4];
        }
        float p = 0.f;
        if (powok) {
            const float a1 = fexp2(dtv_c * A2[0]);
            float a = a1;
#pragma unroll
            for (int s = 0; s < 16; ++s) {
                h[s] = fmaf(a, h[s], dtu * Bv[s]);
                if (PHASE == 1) p = fmaf(h[s], Cv[s], p);
                a *= a1;
            }
        } else {
#pragma unroll
            for (int s = 0; s < 16; ++s) {
                float a = fexp2(dtv_c * A2[s]);
                h[s] = fmaf(a, h[s], dtu * Bv[s]);
                if (PHASE == 1) p = fmaf(h[s], Cv[s], p);
            }
        }
        if (PHASE == 1) {
            ybf[m * 1024 + d] = f2b((p + Dv * uv_c) * silu(zv));
        }
    }
    if (PHASE == 0) {
        float aprod[16];
        if (powok) {
            const float ap1 = fexp2(A2[0] * dtsum);
            float a = ap1;
#pragma unroll
            for (int s = 0; s < 16; ++s) { aprod[s] = a; a *= ap1; }
        } else {
#pragma unroll
            for (int s = 0; s < 16; ++s) aprod[s] = fexp2(A2[s] * dtsum);
        }
        unsigned int pk[16];
#pragma unroll
        for (int s = 0; s < 16; ++s)
            pk[s] = (unsigned int)f2b(aprod[s]) | ((unsigned int)f2b(h[s]) << 16);
#pragma unroll
        for (int s = 0; s < 16; s += 4)
            *(uint4*)(sum + sumbase + s) = *(const uint4*)&pk[s];
    }
}

// carry scan over packed chunk summaries; writes compact bf16 h_init.
__global__ __launch_bounds__(256) void k_scan_carry(const unsigned int* __restrict__ sum,
                                                    unsigned short* __restrict__ hinit) {
    int i = blockIdx.x * 256 + threadIdx.x;   // (b, d*16+s)
    int b = i >> 14, ds = i & 16383;
    float h = 0.f;
    for (int c = 0; c < SCAN_NC; ++c) {
        size_t idx = ((size_t)(b * SCAN_NC + c) << 14) + ds;
        unsigned int u = sum[idx];
        float a = b2f((unsigned short)(u & 0xffffu));
        float f = b2f((unsigned short)(u >> 16));
        hinit[idx] = f2b(h);
        h = fmaf(a, h, f);
    }
}

// ---------------------------------------------------------------------------
extern "C" void kernel_launch(void* const* d_in, const int* in_sizes, int n_in,
                              void* d_out, int out_size, void* d_ws, size_t ws_size,
                              hipStream_t stream) {
    const float* x         = (const float*)d_in[0];
    const float* skip      = (const float*)d_in[1];
    const float* up_w      = (const float*)d_in[2];
    const float* up_b      = (const float*)d_in[3];
    const float* merge_w   = (const float*)d_in[4];
    const float* merge_b   = (const float*)d_in[5];
    const float* ln_w      = (const float*)d_in[6];
    const float* ln_b      = (const float*)d_in[7];
    const float* in_proj_w = (const float*)d_in[8];
    const float* conv_w    = (const float*)d_in[9];
    const float* conv_b    = (const float*)d_in[10];
    const float* x_proj_w  = (const float*)d_in[11];
    const float* dt_proj_w = (const float*)d_in[12];
    const float* dt_proj_b = (const float*)d_in[13];
    const float* A_log     = (const float*)d_in[14];
    const float* D_param   = (const float*)d_in[15];
    const float* out_proj_w= (const float*)d_in[16];
    float* out = (float*)d_out;

    char* ws = (char*)d_ws;
    size_t off = 0;
    auto alloc = [&](size_t bytes) { size_t r = off; off += (bytes + 255) & ~(size_t)255; return r; };

    // persistent
    unsigned short* upT  = (unsigned short*)(ws + alloc(2048ull * 512 * 2));
    unsigned short* mw   = (unsigned short*)(ws + alloc(512ull * 1024 * 2));
    unsigned short* ipw  = (unsigned short*)(ws + alloc(2ull * 2048 * 512 * 2));
    unsigned short* xpw  = (unsigned short*)(ws + alloc(2ull * 64 * 1024 * 2));
    unsigned short* opw  = (unsigned short*)(ws + alloc(2ull * 512 * 1024 * 2));
    unsigned short* xbf  = (unsigned short*)(ws + alloc(4096ull * 512 * 2));
    unsigned short* ubf  = (unsigned short*)(ws + alloc(8192ull * 512 * 2));
    // per-layer arena (stage-1 buffers aliased in)
    unsigned short* xzbf  = (unsigned short*)(ws + alloc(8192ull * 2048 * 2));
    unsigned short* xcbf  = (unsigned short*)(ws + alloc(8192ull * 1024 * 2));
    float*          xdbl  = (float*)(ws + alloc(8192ull * 64 * 4));
    unsigned short* dtbf  = (unsigned short*)(ws + alloc(8192ull * 1024 * 2));
    unsigned short* ybf   = (unsigned short*)(ws + alloc(8192ull * 1024 * 2));
    unsigned int*   scan_sum   = (unsigned int*)(ws + alloc((size_t)SCAN_NC * 8 * 16384 * 4));
    unsigned short* scan_hinit = (unsigned short*)(ws + alloc((size_t)SCAN_NC * 8 * 16384 * 2));
    unsigned short* dtpA  = (unsigned short*)(ws + alloc(8192ull * 128 * 2));
    unsigned short* dtpB  = (unsigned short*)(ws + alloc(1024ull * 128 * 2));
    float*          P      = (float*)xzbf;          // 32MB == 32MB, dead before in_proj
    unsigned short* catbf  = dtbf;                  // 16MB == 16MB, dead before dt GEMM
    float*          merged = (float*)xcbf;          // 16MB == 16MB, dead before conv

    // weight/activation conversions
    k_cvt<<<2048, 256, 0, stream>>>(x, xbf, 4096 * 512);
    k_cvt<<<512, 256, 0, stream>>>(merge_w, mw, 512 * 1024);
    k_cvt<<<2048, 256, 0, stream>>>(in_proj_w, ipw, 2 * 2048 * 512);
    k_cvt<<<128, 256, 0, stream>>>(x_proj_w, xpw, 2 * 64 * 1024);
    k_cvt<<<1024, 256, 0, stream>>>(out_proj_w, opw, 2 * 512 * 1024);
    k_upT<<<dim3(16, 16, 4), dim3(32, 32), 0, stream>>>(up_w, upT);

    // stage 1: transposed-conv as GEMM, assemble cat, merge GEMM, LN
    k_gemm<128, 128, 0><<<dim3(16, 32), 256, 0, stream>>>(xbf, upT, P, nullptr, nullptr,
                                                          4096, 2048, 512);
    k_assemble<<<32768, 256, 0, stream>>>(P, skip, up_b, catbf);
    k_gemm<128, 128, 0><<<dim3(4, 64), 256, 0, stream>>>(catbf, mw, merged, nullptr, merge_b,
                                                         8192, 512, 1024);
    k_ln<<<2048, 256, 0, stream>>>(merged, ln_w, ln_b, ubf);

    // two mamba layers
    for (int li = 0; li < 2; ++li) {
        k_gemm<128, 128, 1><<<dim3(16, 64), 256, 0, stream>>>(ubf, ipw + (size_t)li * 2048 * 512,
                                                              nullptr, xzbf, nullptr, 8192, 2048, 512);
        k_conv<<<8192, 256, 0, stream>>>(xzbf, conv_w + li * 4096, conv_b + li * 1024, xcbf);
        k_gemm<64, 64, 0><<<dim3(1, 128), 256, 0, stream>>>(xcbf, xpw + (size_t)li * 64 * 1024,
                                                            xdbl, nullptr, nullptr, 8192, 64, 1024);
        // dt path: exact split-bf16 GEMM (K=128) + fused hw-softplus -> bf16
        k_dtpackA<<<1024, 256, 0, stream>>>(xdbl, dtpA);
        k_dtpackB<<<128, 256, 0, stream>>>(dt_proj_w + (size_t)li * 32768, dtpB);
        k_gemm<128, 64, 3><<<dim3(16, 64), 256, 0, stream>>>(dtpA, dtpB, nullptr, dtbf,
                                                             dt_proj_b + (size_t)li * 1024,
                                                             8192, 1024, 128);
        const float* Al = A_log + (size_t)li * 1024 * 16;
        const float* Dl = D_param + (size_t)li * 1024;
        k_scan_chunk<0><<<dim3(4, 8, SCAN_NC), 256, 0, stream>>>(
            dtbf, xcbf, xdbl, xzbf, Al, Dl, scan_sum, scan_hinit, ybf);
        k_scan_carry<<<512, 256, 0, stream>>>(scan_sum, scan_hinit);
        k_scan_chunk<1><<<dim3(4, 8, SCAN_NC), 256, 0, stream>>>(
            dtbf, xcbf, xdbl, xzbf, Al, Dl, scan_sum, scan_hinit, ybf);
        if (li == 0)
            k_gemm<128, 128, 1><<<dim3(4, 64), 256, 0, stream>>>(ybf, opw, nullptr, ubf, nullptr,
                                                                 8192, 512, 1024);
        else
            k_gemm<128, 128, 0><<<dim3(4, 64), 256, 0, stream>>>(ybf, opw + (size_t)512 * 1024,
                                                                 out, nullptr, nullptr, 8192, 512, 1024);
    }
}

// Round 21
// 438.956 us; speedup vs baseline: 1.0541x; 1.0312x over previous
//
#include <hip/hip_runtime.h>

#define DEV __device__ __forceinline__

typedef short  bf16x8 __attribute__((ext_vector_type(8)));
typedef float  f32x4  __attribute__((ext_vector_type(4)));

DEV unsigned short f2b(float f) {
    unsigned int u = __float_as_uint(f);
    u += 0x7fffu + ((u >> 16) & 1u);
    return (unsigned short)(u >> 16);
}
DEV float b2f(unsigned short h) { return __uint_as_float((unsigned int)h << 16); }
DEV float silu(float x) { return x / (1.f + __expf(-x)); }
DEV float fexp2(float x) { return __builtin_amdgcn_exp2f(x); }   // raw v_exp_f32
DEV float flog2(float x) { return __builtin_amdgcn_logf(x); }    // raw v_log_f32

// async global->LDS, 16B per lane: HW writes lane l at ldsbase + l*16
typedef const __attribute__((address_space(1))) unsigned int GU32;
typedef __attribute__((address_space(3))) unsigned int LU32;
DEV void gload16(const unsigned short* g, unsigned short* l) {
    __builtin_amdgcn_global_load_lds((GU32*)g, (LU32*)l, 16, 0, 0);
}

// ---------------------------------------------------------------------------
// fused prep: all weight f32->bf16 conversions + dt_proj_w split-bf16 packing
// (single launch; segments are large so branches are wave-uniform)
__global__ __launch_bounds__(256) void k_prep(
        const float* __restrict__ x, const float* __restrict__ merge_w,
        const float* __restrict__ in_proj_w, const float* __restrict__ x_proj_w,
        const float* __restrict__ out_proj_w, const float* __restrict__ dt_proj_w,
        unsigned short* __restrict__ xbf, unsigned short* __restrict__ mw,
        unsigned short* __restrict__ ipw, unsigned short* __restrict__ xpw,
        unsigned short* __restrict__ opw, unsigned short* __restrict__ dtpB) {
    size_t i = (size_t)blockIdx.x * 256 + threadIdx.x;
    const size_t n0 = 524288;           // x: 4096*512/4
    const size_t n1 = n0 + 131072;      // merge_w: 512*1024/4
    const size_t n2 = n1 + 524288;      // in_proj: 2*2048*512/4
    const size_t n3 = n2 + 32768;       // x_proj: 2*64*1024/4
    const size_t n4 = n3 + 262144;      // out_proj: 2*512*1024/4
    const size_t n5 = n4 + 65536;       // dtpackB: 2*1024*32 scalars
    if (i < n4) {
        const float* s; unsigned short* d; size_t j;
        if (i < n0)      { s = x;          d = xbf; j = i; }
        else if (i < n1) { s = merge_w;    d = mw;  j = i - n0; }
        else if (i < n2) { s = in_proj_w;  d = ipw; j = i - n1; }
        else if (i < n3) { s = x_proj_w;   d = xpw; j = i - n2; }
        else             { s = out_proj_w; d = opw; j = i - n3; }
        float4 v = *(const float4*)(s + j * 4);
        ushort4 o = { f2b(v.x), f2b(v.y), f2b(v.z), f2b(v.w) };
        *(ushort4*)(d + j * 4) = o;
    } else if (i < n5) {
        size_t j = i - n4;              // (li*1024+d)*32 + r
        int r = (int)(j & 31);
        size_t dg = j >> 5;             // global d in [0, 2048)
        float xw = dt_proj_w[dg * 32 + r];
        unsigned short wh = f2b(xw);
        unsigned short wl = f2b(xw - b2f(wh));
        size_t base = dg * 128;
        dtpB[base + r]      = wh;
        dtpB[base + 32 + r] = wl;
        dtpB[base + 64 + r] = wl;
        dtpB[base + 96 + r] = wh;
    }
}

// up_w (512 x 512 x 4) [i,o,k] -> upT[(k*512+o)*512 + i] bf16
__global__ void k_upT(const float* __restrict__ up_w, unsigned short* __restrict__ upT) {
    __shared__ float t[32][33];
    int tx = threadIdx.x, ty = threadIdx.y;
    int o0 = blockIdx.x * 32, i0 = blockIdx.y * 32, kz = blockIdx.z;
    t[ty][tx] = up_w[(size_t)(i0 + ty) * 2048 + (o0 + tx) * 4 + kz];
    __syncthreads();
    upT[(size_t)(kz * 512 + o0 + ty) * 512 + i0 + tx] = f2b(t[tx][ty]);
}

// ---------------------------------------------------------------------------
// bf16 MFMA GEMM, NT: C[m,n] = sum_k A[m,k]*B[n,k].  BK=32, 4 waves,
// m97-style global_load_lds staging (linear LDS, 16B/lane).
// XCD-aware block swizzle (T1): contiguous tile chunks per XCD for L2 reuse.
// Tiles: (BM,BN) in {(128,128),(128,64),(64,64)}.
// OUTMODE 0: f32 out, 1: bf16 out, 2: softplus->f32, 3: softplus->bf16,
//         4: f32 out + dtpackA for cols<32 (split-bf16 K=128 operand).
template <int BM, int BN, int OUTMODE>
__global__ __launch_bounds__(256) void k_gemm(const unsigned short* __restrict__ A,
                                              const unsigned short* __restrict__ B,
                                              float* __restrict__ Cf,
                                              unsigned short* __restrict__ Cb,
                                              const float* __restrict__ bias,
                                              int M, int N, int K) {
    constexpr int BK = 32;
    constexpr int WM = (BN == 128) ? 64 : 32;
    constexpr int WN = (BM == 64 && BN == 64) ? 32 : 64;
    constexpr int MI = WM / 16, NI = WN / 16;
    __shared__ unsigned short As[BM * BK];
    __shared__ unsigned short Bs[BN * BK];
    const int tid = threadIdx.x;
    const int wid = tid >> 6, lane = tid & 63;

    // XCD swizzle: hw bids round-robin XCDs; map same-XCD bids to contiguous tiles
    int bid = blockIdx.y * gridDim.x + blockIdx.x;
    const int nwg = gridDim.x * gridDim.y;
    if ((nwg & 7) == 0) {
        int cpx = nwg >> 3;
        bid = (bid & 7) * cpx + (bid >> 3);
    }
    const int bx = bid % gridDim.x, by = bid / gridDim.x;
    const int m0 = by * BM, n0 = bx * BN;

    int wr, wc;
    if (BN == 128)      { wr = wid >> 1; wc = wid & 1; }
    else if (BM == 128) { wr = wid;      wc = 0;       }
    else                { wr = wid & 1;  wc = wid >> 1; }
    const int wm0 = wr * WM, wn0 = wc * WN;
    const int fr = lane & 15, fh = lane >> 4;

    // staging geometry: wave w stages 16-row strips; lane l -> row w*16+(l>>2),
    // col (l&3)*8 ushorts; LDS dest is wave-uniform strip base (linear layout).
    const int srow = wid * 16 + (lane >> 2);
    const int scol = (lane & 3) * 8;
    const unsigned short* Ag = A + (size_t)(m0 + srow) * K + scol;
    const unsigned short* Bg = B + (size_t)(n0 + srow) * K + scol;
    unsigned short* AsB = &As[wid * 16 * BK];
    unsigned short* BsB = &Bs[wid * 16 * BK];

    f32x4 acc[MI][NI];
#pragma unroll
    for (int i = 0; i < MI; ++i)
#pragma unroll
        for (int j = 0; j < NI; ++j) acc[i][j] = (f32x4){0.f, 0.f, 0.f, 0.f};

    for (int k0 = 0; k0 < K; k0 += BK) {
        gload16(Ag + k0, AsB);
        if (BM == 128) gload16(Ag + (size_t)64 * K + k0, AsB + 64 * BK);
        gload16(Bg + k0, BsB);
        if (BN == 128) gload16(Bg + (size_t)64 * K + k0, BsB + 64 * BK);
        __syncthreads();
        bf16x8 av[MI], bv[NI];
#pragma unroll
        for (int mi = 0; mi < MI; ++mi)
            av[mi] = *(const bf16x8*)(&As[(wm0 + mi * 16 + fr) * BK + fh * 8]);
#pragma unroll
        for (int ni = 0; ni < NI; ++ni)
            bv[ni] = *(const bf16x8*)(&Bs[(wn0 + ni * 16 + fr) * BK + fh * 8]);
#pragma unroll
        for (int mi = 0; mi < MI; ++mi)
#pragma unroll
            for (int ni = 0; ni < NI; ++ni)
                acc[mi][ni] = __builtin_amdgcn_mfma_f32_16x16x32_bf16(av[mi], bv[ni],
                                                                      acc[mi][ni], 0, 0, 0);
        __syncthreads();
    }
    constexpr float LOG2E = 1.4426950408889634f;
    constexpr float LN2   = 0.6931471805599453f;
#pragma unroll
    for (int mi = 0; mi < MI; ++mi) {
#pragma unroll
        for (int ni = 0; ni < NI; ++ni) {
            int col = n0 + wn0 + ni * 16 + fr;
            float bb = bias ? bias[col] : 0.f;
#pragma unroll
            for (int j = 0; j < 4; ++j) {
                int row = m0 + wm0 + mi * 16 + fh * 4 + j;
                float v = acc[mi][ni][j] + bb;
                if (OUTMODE == 0)      Cf[(size_t)row * N + col] = v;
                else if (OUTMODE == 1) Cb[(size_t)row * N + col] = f2b(v);
                else if (OUTMODE == 4) {
                    Cf[(size_t)row * N + col] = v;
                    if (col < 32) {
                        unsigned short xh = f2b(v);
                        unsigned short xl = f2b(v - b2f(xh));
                        size_t base = (size_t)row * 128;
                        Cb[base + col]      = xh;
                        Cb[base + 32 + col] = xl;
                        Cb[base + 64 + col] = xh;
                        Cb[base + 96 + col] = xl;
                    }
                } else {
                    float sp = (v > 20.f) ? v : flog2(1.f + fexp2(v * LOG2E)) * LN2;
                    if (OUTMODE == 2) Cf[(size_t)row * N + col] = sp;
                    else              Cb[(size_t)row * N + col] = f2b(sp);
                }
            }
        }
    }
}

// ---------------------------------------------------------------------------
// assemble cat row-major (8192 x 1024) bf16: [0,512)=xu from P, [512,1024)=skip
__global__ __launch_bounds__(256) void k_assemble(const float* __restrict__ P,
                                                  const float* __restrict__ skip,
                                                  const float* __restrict__ up_b,
                                                  unsigned short* __restrict__ catbf) {
    int bx = blockIdx.x;
    int m = bx >> 2;
    int c = (bx & 3) * 256 + threadIdx.x;
    int b = m >> 10, t = m & 1023, j = t >> 1;
    float v;
    if (c < 512) {
        size_t rb = (size_t)((b << 9) + j) * 2048;
        if (t & 1) {                       // odd t: k=2 @ j, k=0 @ j+1
            v = P[rb + 1024 + c];
            if (j + 1 < 512) v += P[rb + 2048 + c];
        } else {                           // even t: k=3 @ j-1, k=1 @ j
            v = P[rb + 512 + c];
            if (j >= 1) v += P[rb - 2048 + 1536 + c];
        }
        v += up_b[c];
    } else {
        v = skip[(size_t)m * 512 + (c - 512)];
    }
    catbf[(size_t)m * 1024 + c] = f2b(v);
}

// LayerNorm over 512, 4 rows per 256-block, writes bf16
__global__ __launch_bounds__(256) void k_ln(const float* __restrict__ merged,
                                            const float* __restrict__ w,
                                            const float* __restrict__ bvec,
                                            unsigned short* __restrict__ outb) {
    int row = blockIdx.x * 4 + (threadIdx.x >> 6);
    int lane = threadIdx.x & 63;
    const float* r = merged + (size_t)row * 512 + lane * 8;
    float4 v1 = *(const float4*)r;
    float4 v2 = *(const float4*)(r + 4);
    float xv[8] = {v1.x, v1.y, v1.z, v1.w, v2.x, v2.y, v2.z, v2.w};
    float s = 0.f, ss = 0.f;
#pragma unroll
    for (int e = 0; e < 8; ++e) { s += xv[e]; ss += xv[e] * xv[e]; }
#pragma unroll
    for (int m = 1; m < 64; m <<= 1) { s += __shfl_xor(s, m, 64); ss += __shfl_xor(ss, m, 64); }
    float mean = s * (1.f / 512.f);
    float var = ss * (1.f / 512.f) - mean * mean;
    float inv = rsqrtf(var + 1e-5f);
    unsigned short o8[8];
#pragma unroll
    for (int e = 0; e < 8; ++e) {
        int c = lane * 8 + e;
        o8[e] = f2b((xv[e] - mean) * inv * w[c] + bvec[c]);
    }
    *(int4*)(outb + (size_t)row * 512 + lane * 8) = *(const int4*)o8;
}

// causal depthwise conv K=4 + bias + silu; 4 channels/thread, bf16 in/out
__global__ __launch_bounds__(256) void k_conv(const unsigned short* __restrict__ xzb,
                                              const float* __restrict__ cw,
                                              const float* __restrict__ cb,
                                              unsigned short* __restrict__ xcb) {
    int i = blockIdx.x * 256 + threadIdx.x;   // 2.1M threads
    int m = i >> 8;
    int c0 = (i & 255) * 4;
    int l = m & 1023;
    float4 w0 = *(const float4*)(cw + (size_t)(c0 + 0) * 4);
    float4 w1 = *(const float4*)(cw + (size_t)(c0 + 1) * 4);
    float4 w2 = *(const float4*)(cw + (size_t)(c0 + 2) * 4);
    float4 w3 = *(const float4*)(cw + (size_t)(c0 + 3) * 4);
    float4 acc = *(const float4*)(cb + c0);
    const float* wp0 = (const float*)&w0;
    const float* wp1 = (const float*)&w1;
    const float* wp2 = (const float*)&w2;
    const float* wp3 = (const float*)&w3;
#pragma unroll
    for (int k = 0; k < 4; ++k) {
        int lp = l - 3 + k;
        if (lp >= 0) {
            ushort4 xv = *(const ushort4*)(xzb + (size_t)(m - l + lp) * 2048 + c0);
            acc.x = fmaf(wp0[k], b2f(xv.x), acc.x);
            acc.y = fmaf(wp1[k], b2f(xv.y), acc.y);
            acc.z = fmaf(wp2[k], b2f(xv.z), acc.z);
            acc.w = fmaf(wp3[k], b2f(xv.w), acc.w);
        }
    }
    ushort4 o = { f2b(silu(acc.x)), f2b(silu(acc.y)), f2b(silu(acc.z)), f2b(silu(acc.w)) };
    *(ushort4*)(xcb + (size_t)m * 1024 + c0) = o;
}

// ---------------------------------------------------------------------------
// Chunked selective scan.  L=1024 split into NC=32 chunks of CL=32.
// Thread = (b, d, chunk), 16 states in registers.  dt/u staged in LDS.
// Summaries COMPRESSED: phase0 stores packed uint32 (bf16 a | bf16 h << 16);
// carry writes compact bf16 h_init; phase1 reads bf16 h_init.
// Power fast path: A[s]=(s+1)*A[0] -> a_s = a1^(s+1) (guarded, exact fallback).
// Block = 256 threads = 256 consecutive d; grid (4 dgrp, 8 b, NC chunk).
constexpr int SCAN_NC = 32;
constexpr int SCAN_CL = 32;

template <int PHASE>
__global__ __launch_bounds__(256) void k_scan_chunk(
        const unsigned short* __restrict__ dtb, const unsigned short* __restrict__ xcb,
        const float* __restrict__ xdbl, const unsigned short* __restrict__ xzb,
        const float* __restrict__ Alog, const float* __restrict__ Dp,
        unsigned int* __restrict__ sum, const unsigned short* __restrict__ hinit,
        unsigned short* __restrict__ ybf) {
    constexpr int CL = SCAN_CL;
    const int tid = threadIdx.x;
    const int d0 = blockIdx.x * 256;
    const int d = d0 + tid;
    const int b = blockIdx.y, c = blockIdx.z;
    const size_t mbase = (size_t)b * 1024 + (size_t)c * CL;

    // bulk-stage chunk inputs into LDS (coalesced 16B chunks, all in flight):
    //   sBC: B/C slice of xdbl; sdt/su: this block's dt/u [CL][256] bf16.
    __shared__ float sBC[CL][32];
    __shared__ unsigned short sdt[CL][256];
    __shared__ unsigned short su[CL][256];
    {
        int row = tid >> 3, q = tid & 7;   // CL*8 == 256
        *(float4*)&sBC[row][q * 4] =
            *(const float4*)(xdbl + (mbase + row) * 64 + 32 + q * 4);
    }
    for (int i = tid; i < CL * 32; i += 256) {       // 32 rows x 32 16B-chunks
        int row = i >> 5, q = i & 31;
        const size_t g = (mbase + row) * 1024 + d0 + q * 8;
        *(int4*)&sdt[row][q * 8] = *(const int4*)(dtb + g);
        *(int4*)&su[row][q * 8]  = *(const int4*)(xcb + g);
    }
    __syncthreads();

    constexpr float LOG2E = 1.4426950408889634f;
    float A2[16], h[16];
#pragma unroll
    for (int s = 0; s < 16; ++s) A2[s] = -expf(Alog[d * 16 + s]) * LOG2E;

    // integer-ratio check: A2[s] == (s+1)*A2[0] to ~1e-5 rel
    bool powok = true;
#pragma unroll
    for (int s = 1; s < 16; ++s)
        powok = powok && (fabsf(A2[s] - (float)(s + 1) * A2[0]) <=
                          1e-5f * fabsf(A2[s]));

    const size_t sumbase = ((size_t)(b * SCAN_NC + c) << 14) + d * 16;
    if (PHASE == 0) {
#pragma unroll
        for (int s = 0; s < 16; ++s) h[s] = 0.f;
    } else {
#pragma unroll
        for (int s = 0; s < 16; s += 8) {
            bf16x8 hv = *(const bf16x8*)(hinit + sumbase + s);
#pragma unroll
            for (int j = 0; j < 8; ++j) h[s + j] = b2f((unsigned short)hv[j]);
        }
    }
    float dtsum = 0.f;
    const float Dv = (PHASE == 1) ? Dp[d] : 0.f;

    // z prefetch one step ahead (phase 1 only)
    float zv_n = 0.f;
    if (PHASE == 1) zv_n = b2f(xzb[mbase * 2048 + 1024 + d]);

#pragma unroll 2
    for (int l = 0; l < CL; ++l) {
        const size_t m = mbase + l;
        const float dtv_c = b2f(sdt[l][tid]);
        const float uv_c  = b2f(su[l][tid]);
        float zv;
        if (PHASE == 1) {
            zv = zv_n;
            if (l + 1 < CL) zv_n = b2f(xzb[(m + 1) * 2048 + 1024 + d]);
        }
        const float dtu = dtv_c * uv_c;
        if (PHASE == 0) dtsum += dtv_c;
        float Bv[16], Cv[16];
#pragma unroll
        for (int q = 0; q < 4; ++q) {
            *(float4*)&Bv[q * 4] = *(const float4*)&sBC[l][q * 4];
            if (PHASE == 1)
                *(float4*)&Cv[q * 4] = *(const float4*)&sBC[l][16 + q * 4];
        }
        float p = 0.f;
        if (powok) {
            const float a1 = fexp2(dtv_c * A2[0]);
            float a = a1;
#pragma unroll
            for (int s = 0; s < 16; ++s) {
                h[s] = fmaf(a, h[s], dtu * Bv[s]);
                if (PHASE == 1) p = fmaf(h[s], Cv[s], p);
                a *= a1;
            }
        } else {
#pragma unroll
            for (int s = 0; s < 16; ++s) {
                float a = fexp2(dtv_c * A2[s]);
                h[s] = fmaf(a, h[s], dtu * Bv[s]);
                if (PHASE == 1) p = fmaf(h[s], Cv[s], p);
            }
        }
        if (PHASE == 1) {
            ybf[m * 1024 + d] = f2b((p + Dv * uv_c) * silu(zv));
        }
    }
    if (PHASE == 0) {
        float aprod[16];
        if (powok) {
            const float ap1 = fexp2(A2[0] * dtsum);
            float a = ap1;
#pragma unroll
            for (int s = 0; s < 16; ++s) { aprod[s] = a; a *= ap1; }
        } else {
#pragma unroll
            for (int s = 0; s < 16; ++s) aprod[s] = fexp2(A2[s] * dtsum);
        }
        unsigned int pk[16];
#pragma unroll
        for (int s = 0; s < 16; ++s)
            pk[s] = (unsigned int)f2b(aprod[s]) | ((unsigned int)f2b(h[s]) << 16);
#pragma unroll
        for (int s = 0; s < 16; s += 4)
            *(uint4*)(sum + sumbase + s) = *(const uint4*)&pk[s];
    }
}

// carry scan over packed chunk summaries; writes compact bf16 h_init.
__global__ __launch_bounds__(256) void k_scan_carry(const unsigned int* __restrict__ sum,
                                                    unsigned short* __restrict__ hinit) {
    int i = blockIdx.x * 256 + threadIdx.x;   // (b, d*16+s)
    int b = i >> 14, ds = i & 16383;
    float h = 0.f;
    for (int c = 0; c < SCAN_NC; ++c) {
        size_t idx = ((size_t)(b * SCAN_NC + c) << 14) + ds;
        unsigned int u = sum[idx];
        float a = b2f((unsigned short)(u & 0xffffu));
        float f = b2f((unsigned short)(u >> 16));
        hinit[idx] = f2b(h);
        h = fmaf(a, h, f);
    }
}

// ---------------------------------------------------------------------------
extern "C" void kernel_launch(void* const* d_in, const int* in_sizes, int n_in,
                              void* d_out, int out_size, void* d_ws, size_t ws_size,
                              hipStream_t stream) {
    const float* x         = (const float*)d_in[0];
    const float* skip      = (const float*)d_in[1];
    const float* up_w      = (const float*)d_in[2];
    const float* up_b      = (const float*)d_in[3];
    const float* merge_w   = (const float*)d_in[4];
    const float* merge_b   = (const float*)d_in[5];
    const float* ln_w      = (const float*)d_in[6];
    const float* ln_b      = (const float*)d_in[7];
    const float* in_proj_w = (const float*)d_in[8];
    const float* conv_w    = (const float*)d_in[9];
    const float* conv_b    = (const float*)d_in[10];
    const float* x_proj_w  = (const float*)d_in[11];
    const float* dt_proj_w = (const float*)d_in[12];
    const float* dt_proj_b = (const float*)d_in[13];
    const float* A_log     = (const float*)d_in[14];
    const float* D_param   = (const float*)d_in[15];
    const float* out_proj_w= (const float*)d_in[16];
    float* out = (float*)d_out;

    char* ws = (char*)d_ws;
    size_t off = 0;
    auto alloc = [&](size_t bytes) { size_t r = off; off += (bytes + 255) & ~(size_t)255; return r; };

    // persistent
    unsigned short* upT  = (unsigned short*)(ws + alloc(2048ull * 512 * 2));
    unsigned short* mw   = (unsigned short*)(ws + alloc(512ull * 1024 * 2));
    unsigned short* ipw  = (unsigned short*)(ws + alloc(2ull * 2048 * 512 * 2));
    unsigned short* xpw  = (unsigned short*)(ws + alloc(2ull * 64 * 1024 * 2));
    unsigned short* opw  = (unsigned short*)(ws + alloc(2ull * 512 * 1024 * 2));
    unsigned short* xbf  = (unsigned short*)(ws + alloc(4096ull * 512 * 2));
    unsigned short* ubf  = (unsigned short*)(ws + alloc(8192ull * 512 * 2));
    // per-layer arena (stage-1 buffers aliased in)
    unsigned short* xzbf  = (unsigned short*)(ws + alloc(8192ull * 2048 * 2));
    unsigned short* xcbf  = (unsigned short*)(ws + alloc(8192ull * 1024 * 2));
    float*          xdbl  = (float*)(ws + alloc(8192ull * 64 * 4));
    unsigned short* dtbf  = (unsigned short*)(ws + alloc(8192ull * 1024 * 2));
    unsigned short* ybf   = (unsigned short*)(ws + alloc(8192ull * 1024 * 2));
    unsigned int*   scan_sum   = (unsigned int*)(ws + alloc((size_t)SCAN_NC * 8 * 16384 * 4));
    unsigned short* scan_hinit = (unsigned short*)(ws + alloc((size_t)SCAN_NC * 8 * 16384 * 2));
    unsigned short* dtpA  = (unsigned short*)(ws + alloc(8192ull * 128 * 2));
    unsigned short* dtpB  = (unsigned short*)(ws + alloc(2048ull * 128 * 2));
    float*          P      = (float*)xzbf;          // 32MB == 32MB, dead before in_proj
    unsigned short* catbf  = dtbf;                  // 16MB == 16MB, dead before dt GEMM
    float*          merged = (float*)xcbf;          // 16MB == 16MB, dead before conv

    // fused weight prep (cvt x/merge/in_proj/x_proj/out_proj + dtpackB both layers)
    k_prep<<<6017, 256, 0, stream>>>(x, merge_w, in_proj_w, x_proj_w, out_proj_w,
                                     dt_proj_w, xbf, mw, ipw, xpw, opw, dtpB);
    k_upT<<<dim3(16, 16, 4), dim3(32, 32), 0, stream>>>(up_w, upT);

    // stage 1: transposed-conv as GEMM, assemble cat, merge GEMM, LN
    k_gemm<128, 128, 0><<<dim3(16, 32), 256, 0, stream>>>(xbf, upT, P, nullptr, nullptr,
                                                          4096, 2048, 512);
    k_assemble<<<32768, 256, 0, stream>>>(P, skip, up_b, catbf);
    k_gemm<128, 128, 0><<<dim3(4, 64), 256, 0, stream>>>(catbf, mw, merged, nullptr, merge_b,
                                                         8192, 512, 1024);
    k_ln<<<2048, 256, 0, stream>>>(merged, ln_w, ln_b, ubf);

    // two mamba layers
    for (int li = 0; li < 2; ++li) {
        k_gemm<128, 128, 1><<<dim3(16, 64), 256, 0, stream>>>(ubf, ipw + (size_t)li * 2048 * 512,
                                                              nullptr, xzbf, nullptr, 8192, 2048, 512);
        k_conv<<<8192, 256, 0, stream>>>(xzbf, conv_w + li * 4096, conv_b + li * 1024, xcbf);
        // x_proj GEMM with fused dtpackA epilogue (cols<32 -> split-bf16 operand)
        k_gemm<64, 64, 4><<<dim3(1, 128), 256, 0, stream>>>(xcbf, xpw + (size_t)li * 64 * 1024,
                                                            xdbl, dtpA, nullptr, 8192, 64, 1024);
        // dt GEMM: exact split-bf16 (K=128) + fused hw-softplus -> bf16
        k_gemm<128, 64, 3><<<dim3(16, 64), 256, 0, stream>>>(dtpA, dtpB + (size_t)li * 1024 * 128,
                                                             nullptr, dtbf,
                                                             dt_proj_b + (size_t)li * 1024,
                                                             8192, 1024, 128);
        const float* Al = A_log + (size_t)li * 1024 * 16;
        const float* Dl = D_param + (size_t)li * 1024;
        k_scan_chunk<0><<<dim3(4, 8, SCAN_NC), 256, 0, stream>>>(
            dtbf, xcbf, xdbl, xzbf, Al, Dl, scan_sum, scan_hinit, ybf);
        k_scan_carry<<<512, 256, 0, stream>>>(scan_sum, scan_hinit);
        k_scan_chunk<1><<<dim3(4, 8, SCAN_NC), 256, 0, stream>>>(
            dtbf, xcbf, xdbl, xzbf, Al, Dl, scan_sum, scan_hinit, ybf);
        if (li == 0)
            k_gemm<128, 128, 1><<<dim3(4, 64), 256, 0, stream>>>(ybf, opw, nullptr, ubf, nullptr,
                                                                 8192, 512, 1024);
        else
            k_gemm<128, 128, 0><<<dim3(4, 64), 256, 0, stream>>>(ybf, opw + (size_t)512 * 1024,
                                                                 out, nullptr, nullptr, 8192, 512, 1024);
    }
}

// Round 22
// 435.876 us; speedup vs baseline: 1.0616x; 1.0071x over previous
//
#include <hip/hip_runtime.h>

#define DEV __device__ __forceinline__

typedef short  bf16x8 __attribute__((ext_vector_type(8)));
typedef float  f32x4  __attribute__((ext_vector_type(4)));

DEV unsigned short f2b(float f) {
    unsigned int u = __float_as_uint(f);
    u += 0x7fffu + ((u >> 16) & 1u);
    return (unsigned short)(u >> 16);
}
DEV float b2f(unsigned short h) { return __uint_as_float((unsigned int)h << 16); }
DEV float silu(float x) { return x / (1.f + __expf(-x)); }
DEV float fexp2(float x) { return __builtin_amdgcn_exp2f(x); }   // raw v_exp_f32
DEV float flog2(float x) { return __builtin_amdgcn_logf(x); }    // raw v_log_f32

// async global->LDS, 16B per lane: HW writes lane l at ldsbase + l*16
typedef const __attribute__((address_space(1))) unsigned int GU32;
typedef __attribute__((address_space(3))) unsigned int LU32;
DEV void gload16(const unsigned short* g, unsigned short* l) {
    __builtin_amdgcn_global_load_lds((GU32*)g, (LU32*)l, 16, 0, 0);
}

// ---------------------------------------------------------------------------
// fused prep: all weight f32->bf16 conversions + dt_proj_w split-bf16 packing
// (single launch; segments are large so branches are wave-uniform)
__global__ __launch_bounds__(256) void k_prep(
        const float* __restrict__ x, const float* __restrict__ merge_w,
        const float* __restrict__ in_proj_w, const float* __restrict__ x_proj_w,
        const float* __restrict__ out_proj_w, const float* __restrict__ dt_proj_w,
        unsigned short* __restrict__ xbf, unsigned short* __restrict__ mw,
        unsigned short* __restrict__ ipw, unsigned short* __restrict__ xpw,
        unsigned short* __restrict__ opw, unsigned short* __restrict__ dtpB) {
    size_t i = (size_t)blockIdx.x * 256 + threadIdx.x;
    const size_t n0 = 524288;           // x: 4096*512/4
    const size_t n1 = n0 + 131072;      // merge_w: 512*1024/4
    const size_t n2 = n1 + 524288;      // in_proj: 2*2048*512/4
    const size_t n3 = n2 + 32768;       // x_proj: 2*64*1024/4
    const size_t n4 = n3 + 262144;      // out_proj: 2*512*1024/4
    const size_t n5 = n4 + 65536;       // dtpackB: 2*1024*32 scalars
    if (i < n4) {
        const float* s; unsigned short* d; size_t j;
        if (i < n0)      { s = x;          d = xbf; j = i; }
        else if (i < n1) { s = merge_w;    d = mw;  j = i - n0; }
        else if (i < n2) { s = in_proj_w;  d = ipw; j = i - n1; }
        else if (i < n3) { s = x_proj_w;   d = xpw; j = i - n2; }
        else             { s = out_proj_w; d = opw; j = i - n3; }
        float4 v = *(const float4*)(s + j * 4);
        ushort4 o = { f2b(v.x), f2b(v.y), f2b(v.z), f2b(v.w) };
        *(ushort4*)(d + j * 4) = o;
    } else if (i < n5) {
        size_t j = i - n4;              // (li*1024+d)*32 + r
        int r = (int)(j & 31);
        size_t dg = j >> 5;             // global d in [0, 2048)
        float xw = dt_proj_w[dg * 32 + r];
        unsigned short wh = f2b(xw);
        unsigned short wl = f2b(xw - b2f(wh));
        size_t base = dg * 128;
        dtpB[base + r]      = wh;
        dtpB[base + 32 + r] = wl;
        dtpB[base + 64 + r] = wl;
        dtpB[base + 96 + r] = wh;
    }
}

// up_w (512 x 512 x 4) [i,o,k] -> upT[(k*512+o)*512 + i] bf16
__global__ void k_upT(const float* __restrict__ up_w, unsigned short* __restrict__ upT) {
    __shared__ float t[32][33];
    int tx = threadIdx.x, ty = threadIdx.y;
    int o0 = blockIdx.x * 32, i0 = blockIdx.y * 32, kz = blockIdx.z;
    t[ty][tx] = up_w[(size_t)(i0 + ty) * 2048 + (o0 + tx) * 4 + kz];
    __syncthreads();
    upT[(size_t)(kz * 512 + o0 + ty) * 512 + i0 + tx] = f2b(t[tx][ty]);
}

// ---------------------------------------------------------------------------
// bf16 MFMA GEMM, NT: C[m,n] = sum_k A[m,k]*B[n,k].  BK=64 (half the barriers
// of BK=32; MFMA K-order identical), 4 waves, m97-style global_load_lds
// staging (linear LDS, 8-row strips, 16B/lane).
// XCD-aware block swizzle (T1): contiguous tile chunks per XCD for L2 reuse.
// Tiles: (BM,BN) in {(128,128),(128,64),(64,64)}.
// OUTMODE 0: f32 out, 1: bf16 out, 2: softplus->f32, 3: softplus->bf16,
//         4: f32 out + dtpackA for cols<32 (split-bf16 K=128 operand).
template <int BM, int BN, int OUTMODE>
__global__ __launch_bounds__(256) void k_gemm(const unsigned short* __restrict__ A,
                                              const unsigned short* __restrict__ B,
                                              float* __restrict__ Cf,
                                              unsigned short* __restrict__ Cb,
                                              const float* __restrict__ bias,
                                              int M, int N, int K) {
    constexpr int BK = 64;
    constexpr int WM = (BN == 128) ? 64 : 32;
    constexpr int WN = (BM == 64 && BN == 64) ? 32 : 64;
    constexpr int MI = WM / 16, NI = WN / 16;
    __shared__ unsigned short As[BM * BK];
    __shared__ unsigned short Bs[BN * BK];
    const int tid = threadIdx.x;
    const int wid = tid >> 6, lane = tid & 63;

    // XCD swizzle: hw bids round-robin XCDs; map same-XCD bids to contiguous tiles
    int bid = blockIdx.y * gridDim.x + blockIdx.x;
    const int nwg = gridDim.x * gridDim.y;
    if ((nwg & 7) == 0) {
        int cpx = nwg >> 3;
        bid = (bid & 7) * cpx + (bid >> 3);
    }
    const int bx = bid % gridDim.x, by = bid / gridDim.x;
    const int m0 = by * BM, n0 = bx * BN;

    int wr, wc;
    if (BN == 128)      { wr = wid >> 1; wc = wid & 1; }
    else if (BM == 128) { wr = wid;      wc = 0;       }
    else                { wr = wid & 1;  wc = wid >> 1; }
    const int wm0 = wr * WM, wn0 = wc * WN;
    const int fr = lane & 15, fh = lane >> 4;

    // staging geometry (BK=64): one gload16 covers 8 rows (64 lanes x 16B);
    // lane l -> row (l>>3), col (l&7)*8 ushorts; wave w owns strip base w*8,
    // stepping 32 rows per call (4 waves x 8 rows).
    const int srow = lane >> 3;
    const int scol = (lane & 7) * 8;
    const unsigned short* Ag = A + (size_t)(m0 + wid * 8 + srow) * K + scol;
    const unsigned short* Bg = B + (size_t)(n0 + wid * 8 + srow) * K + scol;
    unsigned short* AsB = &As[wid * 8 * BK];
    unsigned short* BsB = &Bs[wid * 8 * BK];

    f32x4 acc[MI][NI];
#pragma unroll
    for (int i = 0; i < MI; ++i)
#pragma unroll
        for (int j = 0; j < NI; ++j) acc[i][j] = (f32x4){0.f, 0.f, 0.f, 0.f};

    for (int k0 = 0; k0 < K; k0 += BK) {
#pragma unroll
        for (int i = 0; i < BM / 32; ++i)
            gload16(Ag + (size_t)(i * 32) * K + k0, AsB + i * 32 * BK);
#pragma unroll
        for (int i = 0; i < BN / 32; ++i)
            gload16(Bg + (size_t)(i * 32) * K + k0, BsB + i * 32 * BK);
        __syncthreads();
#pragma unroll
        for (int kk = 0; kk < BK; kk += 32) {
            bf16x8 av[MI], bv[NI];
#pragma unroll
            for (int mi = 0; mi < MI; ++mi)
                av[mi] = *(const bf16x8*)(&As[(wm0 + mi * 16 + fr) * BK + kk + fh * 8]);
#pragma unroll
            for (int ni = 0; ni < NI; ++ni)
                bv[ni] = *(const bf16x8*)(&Bs[(wn0 + ni * 16 + fr) * BK + kk + fh * 8]);
#pragma unroll
            for (int mi = 0; mi < MI; ++mi)
#pragma unroll
                for (int ni = 0; ni < NI; ++ni)
                    acc[mi][ni] = __builtin_amdgcn_mfma_f32_16x16x32_bf16(av[mi], bv[ni],
                                                                          acc[mi][ni], 0, 0, 0);
        }
        __syncthreads();
    }
    constexpr float LOG2E = 1.4426950408889634f;
    constexpr float LN2   = 0.6931471805599453f;
#pragma unroll
    for (int mi = 0; mi < MI; ++mi) {
#pragma unroll
        for (int ni = 0; ni < NI; ++ni) {
            int col = n0 + wn0 + ni * 16 + fr;
            float bb = bias ? bias[col] : 0.f;
#pragma unroll
            for (int j = 0; j < 4; ++j) {
                int row = m0 + wm0 + mi * 16 + fh * 4 + j;
                float v = acc[mi][ni][j] + bb;
                if (OUTMODE == 0)      Cf[(size_t)row * N + col] = v;
                else if (OUTMODE == 1) Cb[(size_t)row * N + col] = f2b(v);
                else if (OUTMODE == 4) {
                    Cf[(size_t)row * N + col] = v;
                    if (col < 32) {
                        unsigned short xh = f2b(v);
                        unsigned short xl = f2b(v - b2f(xh));
                        size_t base = (size_t)row * 128;
                        Cb[base + col]      = xh;
                        Cb[base + 32 + col] = xl;
                        Cb[base + 64 + col] = xh;
                        Cb[base + 96 + col] = xl;
                    }
                } else {
                    float sp = (v > 20.f) ? v : flog2(1.f + fexp2(v * LOG2E)) * LN2;
                    if (OUTMODE == 2) Cf[(size_t)row * N + col] = sp;
                    else              Cb[(size_t)row * N + col] = f2b(sp);
                }
            }
        }
    }
}

// ---------------------------------------------------------------------------
// assemble cat row-major (8192 x 1024) bf16: [0,512)=xu from P, [512,1024)=skip
__global__ __launch_bounds__(256) void k_assemble(const float* __restrict__ P,
                                                  const float* __restrict__ skip,
                                                  const float* __restrict__ up_b,
                                                  unsigned short* __restrict__ catbf) {
    int bx = blockIdx.x;
    int m = bx >> 2;
    int c = (bx & 3) * 256 + threadIdx.x;
    int b = m >> 10, t = m & 1023, j = t >> 1;
    float v;
    if (c < 512) {
        size_t rb = (size_t)((b << 9) + j) * 2048;
        if (t & 1) {                       // odd t: k=2 @ j, k=0 @ j+1
            v = P[rb + 1024 + c];
            if (j + 1 < 512) v += P[rb + 2048 + c];
        } else {                           // even t: k=3 @ j-1, k=1 @ j
            v = P[rb + 512 + c];
            if (j >= 1) v += P[rb - 2048 + 1536 + c];
        }
        v += up_b[c];
    } else {
        v = skip[(size_t)m * 512 + (c - 512)];
    }
    catbf[(size_t)m * 1024 + c] = f2b(v);
}

// LayerNorm over 512, 4 rows per 256-block, writes bf16
__global__ __launch_bounds__(256) void k_ln(const float* __restrict__ merged,
                                            const float* __restrict__ w,
                                            const float* __restrict__ bvec,
                                            unsigned short* __restrict__ outb) {
    int row = blockIdx.x * 4 + (threadIdx.x >> 6);
    int lane = threadIdx.x & 63;
    const float* r = merged + (size_t)row * 512 + lane * 8;
    float4 v1 = *(const float4*)r;
    float4 v2 = *(const float4*)(r + 4);
    float xv[8] = {v1.x, v1.y, v1.z, v1.w, v2.x, v2.y, v2.z, v2.w};
    float s = 0.f, ss = 0.f;
#pragma unroll
    for (int e = 0; e < 8; ++e) { s += xv[e]; ss += xv[e] * xv[e]; }
#pragma unroll
    for (int m = 1; m < 64; m <<= 1) { s += __shfl_xor(s, m, 64); ss += __shfl_xor(ss, m, 64); }
    float mean = s * (1.f / 512.f);
    float var = ss * (1.f / 512.f) - mean * mean;
    float inv = rsqrtf(var + 1e-5f);
    unsigned short o8[8];
#pragma unroll
    for (int e = 0; e < 8; ++e) {
        int c = lane * 8 + e;
        o8[e] = f2b((xv[e] - mean) * inv * w[c] + bvec[c]);
    }
    *(int4*)(outb + (size_t)row * 512 + lane * 8) = *(const int4*)o8;
}

// causal depthwise conv K=4 + bias + silu; 4 channels/thread, bf16 in/out
__global__ __launch_bounds__(256) void k_conv(const unsigned short* __restrict__ xzb,
                                              const float* __restrict__ cw,
                                              const float* __restrict__ cb,
                                              unsigned short* __restrict__ xcb) {
    int i = blockIdx.x * 256 + threadIdx.x;   // 2.1M threads
    int m = i >> 8;
    int c0 = (i & 255) * 4;
    int l = m & 1023;
    float4 w0 = *(const float4*)(cw + (size_t)(c0 + 0) * 4);
    float4 w1 = *(const float4*)(cw + (size_t)(c0 + 1) * 4);
    float4 w2 = *(const float4*)(cw + (size_t)(c0 + 2) * 4);
    float4 w3 = *(const float4*)(cw + (size_t)(c0 + 3) * 4);
    float4 acc = *(const float4*)(cb + c0);
    const float* wp0 = (const float*)&w0;
    const float* wp1 = (const float*)&w1;
    const float* wp2 = (const float*)&w2;
    const float* wp3 = (const float*)&w3;
#pragma unroll
    for (int k = 0; k < 4; ++k) {
        int lp = l - 3 + k;
        if (lp >= 0) {
            ushort4 xv = *(const ushort4*)(xzb + (size_t)(m - l + lp) * 2048 + c0);
            acc.x = fmaf(wp0[k], b2f(xv.x), acc.x);
            acc.y = fmaf(wp1[k], b2f(xv.y), acc.y);
            acc.z = fmaf(wp2[k], b2f(xv.z), acc.z);
            acc.w = fmaf(wp3[k], b2f(xv.w), acc.w);
        }
    }
    ushort4 o = { f2b(silu(acc.x)), f2b(silu(acc.y)), f2b(silu(acc.z)), f2b(silu(acc.w)) };
    *(ushort4*)(xcb + (size_t)m * 1024 + c0) = o;
}

// ---------------------------------------------------------------------------
// Chunked selective scan.  L=1024 split into NC=32 chunks of CL=32.
// Thread = (b, d, chunk), 16 states in registers.  dt/u staged in LDS.
// Summaries COMPRESSED: phase0 stores packed uint32 (bf16 a | bf16 h << 16);
// carry writes compact bf16 h_init; phase1 reads bf16 h_init.
// Power fast path: A[s]=(s+1)*A[0] -> a_s = a1^(s+1) (guarded, exact fallback).
// Block = 256 threads = 256 consecutive d; grid (4 dgrp, 8 b, NC chunk).
constexpr int SCAN_NC = 32;
constexpr int SCAN_CL = 32;

template <int PHASE>
__global__ __launch_bounds__(256) void k_scan_chunk(
        const unsigned short* __restrict__ dtb, const unsigned short* __restrict__ xcb,
        const float* __restrict__ xdbl, const unsigned short* __restrict__ xzb,
        const float* __restrict__ Alog, const float* __restrict__ Dp,
        unsigned int* __restrict__ sum, const unsigned short* __restrict__ hinit,
        unsigned short* __restrict__ ybf) {
    constexpr int CL = SCAN_CL;
    const int tid = threadIdx.x;
    const int d0 = blockIdx.x * 256;
    const int d = d0 + tid;
    const int b = blockIdx.y, c = blockIdx.z;
    const size_t mbase = (size_t)b * 1024 + (size_t)c * CL;

    // bulk-stage chunk inputs into LDS (coalesced 16B chunks, all in flight):
    //   sBC: B/C slice of xdbl; sdt/su: this block's dt/u [CL][256] bf16.
    __shared__ float sBC[CL][32];
    __shared__ unsigned short sdt[CL][256];
    __shared__ unsigned short su[CL][256];
    {
        int row = tid >> 3, q = tid & 7;   // CL*8 == 256
        *(float4*)&sBC[row][q * 4] =
            *(const float4*)(xdbl + (mbase + row) * 64 + 32 + q * 4);
    }
    for (int i = tid; i < CL * 32; i += 256) {       // 32 rows x 32 16B-chunks
        int row = i >> 5, q = i & 31;
        const size_t g = (mbase + row) * 1024 + d0 + q * 8;
        *(int4*)&sdt[row][q * 8] = *(const int4*)(dtb + g);
        *(int4*)&su[row][q * 8]  = *(const int4*)(xcb + g);
    }
    __syncthreads();

    constexpr float LOG2E = 1.4426950408889634f;
    float A2[16], h[16];
#pragma unroll
    for (int s = 0; s < 16; ++s) A2[s] = -expf(Alog[d * 16 + s]) * LOG2E;

    // integer-ratio check: A2[s] == (s+1)*A2[0] to ~1e-5 rel
    bool powok = true;
#pragma unroll
    for (int s = 1; s < 16; ++s)
        powok = powok && (fabsf(A2[s] - (float)(s + 1) * A2[0]) <=
                          1e-5f * fabsf(A2[s]));

    const size_t sumbase = ((size_t)(b * SCAN_NC + c) << 14) + d * 16;
    if (PHASE == 0) {
#pragma unroll
        for (int s = 0; s < 16; ++s) h[s] = 0.f;
    } else {
#pragma unroll
        for (int s = 0; s < 16; s += 8) {
            bf16x8 hv = *(const bf16x8*)(hinit + sumbase + s);
#pragma unroll
            for (int j = 0; j < 8; ++j) h[s + j] = b2f((unsigned short)hv[j]);
        }
    }
    float dtsum = 0.f;
    const float Dv = (PHASE == 1) ? Dp[d] : 0.f;

    // z prefetch one step ahead (phase 1 only)
    float zv_n = 0.f;
    if (PHASE == 1) zv_n = b2f(xzb[mbase * 2048 + 1024 + d]);

#pragma unroll 2
    for (int l = 0; l < CL; ++l) {
        const size_t m = mbase + l;
        const float dtv_c = b2f(sdt[l][tid]);
        const float uv_c  = b2f(su[l][tid]);
        float zv;
        if (PHASE == 1) {
            zv = zv_n;
            if (l + 1 < CL) zv_n = b2f(xzb[(m + 1) * 2048 + 1024 + d]);
        }
        const float dtu = dtv_c * uv_c;
        if (PHASE == 0) dtsum += dtv_c;
        float Bv[16], Cv[16];
#pragma unroll
        for (int q = 0; q < 4; ++q) {
            *(float4*)&Bv[q * 4] = *(const float4*)&sBC[l][q * 4];
            if (PHASE == 1)
                *(float4*)&Cv[q * 4] = *(const float4*)&sBC[l][16 + q * 4];
        }
        float p = 0.f;
        if (powok) {
            const float a1 = fexp2(dtv_c * A2[0]);
            float a = a1;
#pragma unroll
            for (int s = 0; s < 16; ++s) {
                h[s] = fmaf(a, h[s], dtu * Bv[s]);
                if (PHASE == 1) p = fmaf(h[s], Cv[s], p);
                a *= a1;
            }
        } else {
#pragma unroll
            for (int s = 0; s < 16; ++s) {
                float a = fexp2(dtv_c * A2[s]);
                h[s] = fmaf(a, h[s], dtu * Bv[s]);
                if (PHASE == 1) p = fmaf(h[s], Cv[s], p);
            }
        }
        if (PHASE == 1) {
            ybf[m * 1024 + d] = f2b((p + Dv * uv_c) * silu(zv));
        }
    }
    if (PHASE == 0) {
        float aprod[16];
        if (powok) {
            const float ap1 = fexp2(A2[0] * dtsum);
            float a = ap1;
#pragma unroll
            for (int s = 0; s < 16; ++s) { aprod[s] = a; a *= ap1; }
        } else {
#pragma unroll
            for (int s = 0; s < 16; ++s) aprod[s] = fexp2(A2[s] * dtsum);
        }
        unsigned int pk[16];
#pragma unroll
        for (int s = 0; s < 16; ++s)
            pk[s] = (unsigned int)f2b(aprod[s]) | ((unsigned int)f2b(h[s]) << 16);
#pragma unroll
        for (int s = 0; s < 16; s += 4)
            *(uint4*)(sum + sumbase + s) = *(const uint4*)&pk[s];
    }
}

// carry scan over packed chunk summaries; writes compact bf16 h_init.
__global__ __launch_bounds__(256) void k_scan_carry(const unsigned int* __restrict__ sum,
                                                    unsigned short* __restrict__ hinit) {
    int i = blockIdx.x * 256 + threadIdx.x;   // (b, d*16+s)
    int b = i >> 14, ds = i & 16383;
    float h = 0.f;
    for (int c = 0; c < SCAN_NC; ++c) {
        size_t idx = ((size_t)(b * SCAN_NC + c) << 14) + ds;
        unsigned int u = sum[idx];
        float a = b2f((unsigned short)(u & 0xffffu));
        float f = b2f((unsigned short)(u >> 16));
        hinit[idx] = f2b(h);
        h = fmaf(a, h, f);
    }
}

// ---------------------------------------------------------------------------
extern "C" void kernel_launch(void* const* d_in, const int* in_sizes, int n_in,
                              void* d_out, int out_size, void* d_ws, size_t ws_size,
                              hipStream_t stream) {
    const float* x         = (const float*)d_in[0];
    const float* skip      = (const float*)d_in[1];
    const float* up_w      = (const float*)d_in[2];
    const float* up_b      = (const float*)d_in[3];
    const float* merge_w   = (const float*)d_in[4];
    const float* merge_b   = (const float*)d_in[5];
    const float* ln_w      = (const float*)d_in[6];
    const float* ln_b      = (const float*)d_in[7];
    const float* in_proj_w = (const float*)d_in[8];
    const float* conv_w    = (const float*)d_in[9];
    const float* conv_b    = (const float*)d_in[10];
    const float* x_proj_w  = (const float*)d_in[11];
    const float* dt_proj_w = (const float*)d_in[12];
    const float* dt_proj_b = (const float*)d_in[13];
    const float* A_log     = (const float*)d_in[14];
    const float* D_param   = (const float*)d_in[15];
    const float* out_proj_w= (const float*)d_in[16];
    float* out = (float*)d_out;

    char* ws = (char*)d_ws;
    size_t off = 0;
    auto alloc = [&](size_t bytes) { size_t r = off; off += (bytes + 255) & ~(size_t)255; return r; };

    // persistent
    unsigned short* upT  = (unsigned short*)(ws + alloc(2048ull * 512 * 2));
    unsigned short* mw   = (unsigned short*)(ws + alloc(512ull * 1024 * 2));
    unsigned short* ipw  = (unsigned short*)(ws + alloc(2ull * 2048 * 512 * 2));
    unsigned short* xpw  = (unsigned short*)(ws + alloc(2ull * 64 * 1024 * 2));
    unsigned short* opw  = (unsigned short*)(ws + alloc(2ull * 512 * 1024 * 2));
    unsigned short* xbf  = (unsigned short*)(ws + alloc(4096ull * 512 * 2));
    unsigned short* ubf  = (unsigned short*)(ws + alloc(8192ull * 512 * 2));
    // per-layer arena (stage-1 buffers aliased in)
    unsigned short* xzbf  = (unsigned short*)(ws + alloc(8192ull * 2048 * 2));
    unsigned short* xcbf  = (unsigned short*)(ws + alloc(8192ull * 1024 * 2));
    float*          xdbl  = (float*)(ws + alloc(8192ull * 64 * 4));
    unsigned short* dtbf  = (unsigned short*)(ws + alloc(8192ull * 1024 * 2));
    unsigned short* ybf   = (unsigned short*)(ws + alloc(8192ull * 1024 * 2));
    unsigned int*   scan_sum   = (unsigned int*)(ws + alloc((size_t)SCAN_NC * 8 * 16384 * 4));
    unsigned short* scan_hinit = (unsigned short*)(ws + alloc((size_t)SCAN_NC * 8 * 16384 * 2));
    unsigned short* dtpA  = (unsigned short*)(ws + alloc(8192ull * 128 * 2));
    unsigned short* dtpB  = (unsigned short*)(ws + alloc(2048ull * 128 * 2));
    float*          P      = (float*)xzbf;          // 32MB == 32MB, dead before in_proj
    unsigned short* catbf  = dtbf;                  // 16MB == 16MB, dead before dt GEMM
    float*          merged = (float*)xcbf;          // 16MB == 16MB, dead before conv

    // fused weight prep (cvt x/merge/in_proj/x_proj/out_proj + dtpackB both layers)
    k_prep<<<6017, 256, 0, stream>>>(x, merge_w, in_proj_w, x_proj_w, out_proj_w,
                                     dt_proj_w, xbf, mw, ipw, xpw, opw, dtpB);
    k_upT<<<dim3(16, 16, 4), dim3(32, 32), 0, stream>>>(up_w, upT);

    // stage 1: transposed-conv as GEMM, assemble cat, merge GEMM, LN
    k_gemm<128, 128, 0><<<dim3(16, 32), 256, 0, stream>>>(xbf, upT, P, nullptr, nullptr,
                                                          4096, 2048, 512);
    k_assemble<<<32768, 256, 0, stream>>>(P, skip, up_b, catbf);
    k_gemm<128, 128, 0><<<dim3(4, 64), 256, 0, stream>>>(catbf, mw, merged, nullptr, merge_b,
                                                         8192, 512, 1024);
    k_ln<<<2048, 256, 0, stream>>>(merged, ln_w, ln_b, ubf);

    // two mamba layers
    for (int li = 0; li < 2; ++li) {
        k_gemm<128, 128, 1><<<dim3(16, 64), 256, 0, stream>>>(ubf, ipw + (size_t)li * 2048 * 512,
                                                              nullptr, xzbf, nullptr, 8192, 2048, 512);
        k_conv<<<8192, 256, 0, stream>>>(xzbf, conv_w + li * 4096, conv_b + li * 1024, xcbf);
        // x_proj GEMM with fused dtpackA epilogue (cols<32 -> split-bf16 operand)
        k_gemm<64, 64, 4><<<dim3(1, 128), 256, 0, stream>>>(xcbf, xpw + (size_t)li * 64 * 1024,
                                                            xdbl, dtpA, nullptr, 8192, 64, 1024);
        // dt GEMM: exact split-bf16 (K=128) + fused hw-softplus -> bf16
        k_gemm<128, 64, 3><<<dim3(16, 64), 256, 0, stream>>>(dtpA, dtpB + (size_t)li * 1024 * 128,
                                                             nullptr, dtbf,
                                                             dt_proj_b + (size_t)li * 1024,
                                                             8192, 1024, 128);
        const float* Al = A_log + (size_t)li * 1024 * 16;
        const float* Dl = D_param + (size_t)li * 1024;
        k_scan_chunk<0><<<dim3(4, 8, SCAN_NC), 256, 0, stream>>>(
            dtbf, xcbf, xdbl, xzbf, Al, Dl, scan_sum, scan_hinit, ybf);
        k_scan_carry<<<512, 256, 0, stream>>>(scan_sum, scan_hinit);
        k_scan_chunk<1><<<dim3(4, 8, SCAN_NC), 256, 0, stream>>>(
            dtbf, xcbf, xdbl, xzbf, Al, Dl, scan_sum, scan_hinit, ybf);
        if (li == 0)
            k_gemm<128, 128, 1><<<dim3(4, 64), 256, 0, stream>>>(ybf, opw, nullptr, ubf, nullptr,
                                                                 8192, 512, 1024);
        else
            k_gemm<128, 128, 0><<<dim3(4, 64), 256, 0, stream>>>(ybf, opw + (size_t)512 * 1024,
                                                                 out, nullptr, nullptr, 8192, 512, 1024);
    }
}

// Round 23
// 408.350 us; speedup vs baseline: 1.1331x; 1.0674x over previous
//
#include <hip/hip_runtime.h>

#define DEV __device__ __forceinline__

typedef short  bf16x8 __attribute__((ext_vector_type(8)));
typedef float  f32x4  __attribute__((ext_vector_type(4)));

DEV unsigned short f2b(float f) {
    unsigned int u = __float_as_uint(f);
    u += 0x7fffu + ((u >> 16) & 1u);
    return (unsigned short)(u >> 16);
}
DEV float b2f(unsigned short h) { return __uint_as_float((unsigned int)h << 16); }
DEV float silu(float x) { return x / (1.f + __expf(-x)); }
DEV float fexp2(float x) { return __builtin_amdgcn_exp2f(x); }   // raw v_exp_f32
DEV float flog2(float x) { return __builtin_amdgcn_logf(x); }    // raw v_log_f32

// async global->LDS, 16B per lane: HW writes lane l at ldsbase + l*16
typedef const __attribute__((address_space(1))) unsigned int GU32;
typedef __attribute__((address_space(3))) unsigned int LU32;
DEV void gload16(const unsigned short* g, unsigned short* l) {
    __builtin_amdgcn_global_load_lds((GU32*)g, (LU32*)l, 16, 0, 0);
}

// ---------------------------------------------------------------------------
// fused prep: all weight f32->bf16 conversions + dt_proj_w split-bf16 packing
// (single launch; segments are large so branches are wave-uniform)
__global__ __launch_bounds__(256) void k_prep(
        const float* __restrict__ x, const float* __restrict__ merge_w,
        const float* __restrict__ in_proj_w, const float* __restrict__ x_proj_w,
        const float* __restrict__ out_proj_w, const float* __restrict__ dt_proj_w,
        unsigned short* __restrict__ xbf, unsigned short* __restrict__ mw,
        unsigned short* __restrict__ ipw, unsigned short* __restrict__ xpw,
        unsigned short* __restrict__ opw, unsigned short* __restrict__ dtpB) {
    size_t i = (size_t)blockIdx.x * 256 + threadIdx.x;
    const size_t n0 = 524288;           // x: 4096*512/4
    const size_t n1 = n0 + 131072;      // merge_w: 512*1024/4
    const size_t n2 = n1 + 524288;      // in_proj: 2*2048*512/4
    const size_t n3 = n2 + 32768;       // x_proj: 2*64*1024/4
    const size_t n4 = n3 + 262144;      // out_proj: 2*512*1024/4
    const size_t n5 = n4 + 65536;       // dtpackB: 2*1024*32 scalars
    if (i < n4) {
        const float* s; unsigned short* d; size_t j;
        if (i < n0)      { s = x;          d = xbf; j = i; }
        else if (i < n1) { s = merge_w;    d = mw;  j = i - n0; }
        else if (i < n2) { s = in_proj_w;  d = ipw; j = i - n1; }
        else if (i < n3) { s = x_proj_w;   d = xpw; j = i - n2; }
        else             { s = out_proj_w; d = opw; j = i - n3; }
        float4 v = *(const float4*)(s + j * 4);
        ushort4 o = { f2b(v.x), f2b(v.y), f2b(v.z), f2b(v.w) };
        *(ushort4*)(d + j * 4) = o;
    } else if (i < n5) {
        size_t j = i - n4;              // (li*1024+d)*32 + r
        int r = (int)(j & 31);
        size_t dg = j >> 5;             // global d in [0, 2048)
        float xw = dt_proj_w[dg * 32 + r];
        unsigned short wh = f2b(xw);
        unsigned short wl = f2b(xw - b2f(wh));
        size_t base = dg * 128;
        dtpB[base + r]      = wh;
        dtpB[base + 32 + r] = wl;
        dtpB[base + 64 + r] = wl;
        dtpB[base + 96 + r] = wh;
    }
}

// up_w (512 x 512 x 4) [i,o,k] -> upT[(k*512+o)*512 + i] bf16
__global__ void k_upT(const float* __restrict__ up_w, unsigned short* __restrict__ upT) {
    __shared__ float t[32][33];
    int tx = threadIdx.x, ty = threadIdx.y;
    int o0 = blockIdx.x * 32, i0 = blockIdx.y * 32, kz = blockIdx.z;
    t[ty][tx] = up_w[(size_t)(i0 + ty) * 2048 + (o0 + tx) * 4 + kz];
    __syncthreads();
    upT[(size_t)(kz * 512 + o0 + ty) * 512 + i0 + tx] = f2b(t[tx][ty]);
}

// ---------------------------------------------------------------------------
// bf16 MFMA GEMM, NT: C[m,n] = sum_k A[m,k]*B[n,k].  BK=64, 4 waves,
// global_load_lds staging with T2 XOR-swizzle (rule #21: linear LDS dest +
// inverse-swizzled GLOBAL source + swizzled READ). Row stride 128B would be a
// same-bank conflict; chunk ^= row&7 spreads 8 lanes over 8 distinct slots.
// XCD-aware block swizzle (T1): contiguous tile chunks per XCD for L2 reuse.
// Tiles: (BM,BN) in {(128,128),(128,64),(64,64)}.
// OUTMODE 0: f32 out, 1: bf16 out, 2: softplus->f32, 3: softplus->bf16,
//         4: f32 out + dtpackA for cols<32 (split-bf16 K=128 operand).
template <int BM, int BN, int OUTMODE>
__global__ __launch_bounds__(256) void k_gemm(const unsigned short* __restrict__ A,
                                              const unsigned short* __restrict__ B,
                                              float* __restrict__ Cf,
                                              unsigned short* __restrict__ Cb,
                                              const float* __restrict__ bias,
                                              int M, int N, int K) {
    constexpr int BK = 64;
    constexpr int WM = (BN == 128) ? 64 : 32;
    constexpr int WN = (BM == 64 && BN == 64) ? 32 : 64;
    constexpr int MI = WM / 16, NI = WN / 16;
    __shared__ unsigned short As[BM * BK];
    __shared__ unsigned short Bs[BN * BK];
    const int tid = threadIdx.x;
    const int wid = tid >> 6, lane = tid & 63;

    // XCD swizzle: hw bids round-robin XCDs; map same-XCD bids to contiguous tiles
    int bid = blockIdx.y * gridDim.x + blockIdx.x;
    const int nwg = gridDim.x * gridDim.y;
    if ((nwg & 7) == 0) {
        int cpx = nwg >> 3;
        bid = (bid & 7) * cpx + (bid >> 3);
    }
    const int bx = bid % gridDim.x, by = bid / gridDim.x;
    const int m0 = by * BM, n0 = bx * BN;

    int wr, wc;
    if (BN == 128)      { wr = wid >> 1; wc = wid & 1; }
    else if (BM == 128) { wr = wid;      wc = 0;       }
    else                { wr = wid & 1;  wc = wid >> 1; }
    const int wm0 = wr * WM, wn0 = wc * WN;
    const int fr = lane & 15, fh = lane >> 4;

    // staging (BK=64): one gload16 covers 8 rows; lane l -> row (l>>3).
    // Global source col chunk pre-swizzled: chunk = (l&7) ^ (l>>3), because
    // staged rows step by 32 so (row & 7) == (l>>3) for this lane always.
    const int srow = lane >> 3;
    const int scol = (((lane & 7) ^ srow)) * 8;
    const unsigned short* Ag = A + (size_t)(m0 + wid * 8 + srow) * K + scol;
    const unsigned short* Bg = B + (size_t)(n0 + wid * 8 + srow) * K + scol;
    unsigned short* AsB = &As[wid * 8 * BK];
    unsigned short* BsB = &Bs[wid * 8 * BK];

    f32x4 acc[MI][NI];
#pragma unroll
    for (int i = 0; i < MI; ++i)
#pragma unroll
        for (int j = 0; j < NI; ++j) acc[i][j] = (f32x4){0.f, 0.f, 0.f, 0.f};

    const int frx = fr & 7;   // read-side XOR factor (row & 7)
    for (int k0 = 0; k0 < K; k0 += BK) {
#pragma unroll
        for (int i = 0; i < BM / 32; ++i)
            gload16(Ag + (size_t)(i * 32) * K + k0, AsB + i * 32 * BK);
#pragma unroll
        for (int i = 0; i < BN / 32; ++i)
            gload16(Bg + (size_t)(i * 32) * K + k0, BsB + i * 32 * BK);
        __syncthreads();
#pragma unroll
        for (int kk = 0; kk < BK; kk += 32) {
            bf16x8 av[MI], bv[NI];
#pragma unroll
            for (int mi = 0; mi < MI; ++mi)
                av[mi] = *(const bf16x8*)(&As[(wm0 + mi * 16 + fr) * BK +
                                              ((((kk >> 3) + fh) ^ frx) << 3)]);
#pragma unroll
            for (int ni = 0; ni < NI; ++ni)
                bv[ni] = *(const bf16x8*)(&Bs[(wn0 + ni * 16 + fr) * BK +
                                              ((((kk >> 3) + fh) ^ frx) << 3)]);
#pragma unroll
            for (int mi = 0; mi < MI; ++mi)
#pragma unroll
                for (int ni = 0; ni < NI; ++ni)
                    acc[mi][ni] = __builtin_amdgcn_mfma_f32_16x16x32_bf16(av[mi], bv[ni],
                                                                          acc[mi][ni], 0, 0, 0);
        }
        __syncthreads();
    }
    constexpr float LOG2E = 1.4426950408889634f;
    constexpr float LN2   = 0.6931471805599453f;
#pragma unroll
    for (int mi = 0; mi < MI; ++mi) {
#pragma unroll
        for (int ni = 0; ni < NI; ++ni) {
            int col = n0 + wn0 + ni * 16 + fr;
            float bb = bias ? bias[col] : 0.f;
#pragma unroll
            for (int j = 0; j < 4; ++j) {
                int row = m0 + wm0 + mi * 16 + fh * 4 + j;
                float v = acc[mi][ni][j] + bb;
                if (OUTMODE == 0)      Cf[(size_t)row * N + col] = v;
                else if (OUTMODE == 1) Cb[(size_t)row * N + col] = f2b(v);
                else if (OUTMODE == 4) {
                    Cf[(size_t)row * N + col] = v;
                    if (col < 32) {
                        unsigned short xh = f2b(v);
                        unsigned short xl = f2b(v - b2f(xh));
                        size_t base = (size_t)row * 128;
                        Cb[base + col]      = xh;
                        Cb[base + 32 + col] = xl;
                        Cb[base + 64 + col] = xh;
                        Cb[base + 96 + col] = xl;
                    }
                } else {
                    float sp = (v > 20.f) ? v : flog2(1.f + fexp2(v * LOG2E)) * LN2;
                    if (OUTMODE == 2) Cf[(size_t)row * N + col] = sp;
                    else              Cb[(size_t)row * N + col] = f2b(sp);
                }
            }
        }
    }
}

// ---------------------------------------------------------------------------
// assemble cat row-major (8192 x 1024) bf16: [0,512)=xu from P, [512,1024)=skip
__global__ __launch_bounds__(256) void k_assemble(const float* __restrict__ P,
                                                  const float* __restrict__ skip,
                                                  const float* __restrict__ up_b,
                                                  unsigned short* __restrict__ catbf) {
    int bx = blockIdx.x;
    int m = bx >> 2;
    int c = (bx & 3) * 256 + threadIdx.x;
    int b = m >> 10, t = m & 1023, j = t >> 1;
    float v;
    if (c < 512) {
        size_t rb = (size_t)((b << 9) + j) * 2048;
        if (t & 1) {                       // odd t: k=2 @ j, k=0 @ j+1
            v = P[rb + 1024 + c];
            if (j + 1 < 512) v += P[rb + 2048 + c];
        } else {                           // even t: k=3 @ j-1, k=1 @ j
            v = P[rb + 512 + c];
            if (j >= 1) v += P[rb - 2048 + 1536 + c];
        }
        v += up_b[c];
    } else {
        v = skip[(size_t)m * 512 + (c - 512)];
    }
    catbf[(size_t)m * 1024 + c] = f2b(v);
}

// LayerNorm over 512, 4 rows per 256-block, writes bf16
__global__ __launch_bounds__(256) void k_ln(const float* __restrict__ merged,
                                            const float* __restrict__ w,
                                            const float* __restrict__ bvec,
                                            unsigned short* __restrict__ outb) {
    int row = blockIdx.x * 4 + (threadIdx.x >> 6);
    int lane = threadIdx.x & 63;
    const float* r = merged + (size_t)row * 512 + lane * 8;
    float4 v1 = *(const float4*)r;
    float4 v2 = *(const float4*)(r + 4);
    float xv[8] = {v1.x, v1.y, v1.z, v1.w, v2.x, v2.y, v2.z, v2.w};
    float s = 0.f, ss = 0.f;
#pragma unroll
    for (int e = 0; e < 8; ++e) { s += xv[e]; ss += xv[e] * xv[e]; }
#pragma unroll
    for (int m = 1; m < 64; m <<= 1) { s += __shfl_xor(s, m, 64); ss += __shfl_xor(ss, m, 64); }
    float mean = s * (1.f / 512.f);
    float var = ss * (1.f / 512.f) - mean * mean;
    float inv = rsqrtf(var + 1e-5f);
    unsigned short o8[8];
#pragma unroll
    for (int e = 0; e < 8; ++e) {
        int c = lane * 8 + e;
        o8[e] = f2b((xv[e] - mean) * inv * w[c] + bvec[c]);
    }
    *(int4*)(outb + (size_t)row * 512 + lane * 8) = *(const int4*)o8;
}

// causal depthwise conv K=4 + bias + silu; 4 channels/thread, bf16 in/out
__global__ __launch_bounds__(256) void k_conv(const unsigned short* __restrict__ xzb,
                                              const float* __restrict__ cw,
                                              const float* __restrict__ cb,
                                              unsigned short* __restrict__ xcb) {
    int i = blockIdx.x * 256 + threadIdx.x;   // 2.1M threads
    int m = i >> 8;
    int c0 = (i & 255) * 4;
    int l = m & 1023;
    float4 w0 = *(const float4*)(cw + (size_t)(c0 + 0) * 4);
    float4 w1 = *(const float4*)(cw + (size_t)(c0 + 1) * 4);
    float4 w2 = *(const float4*)(cw + (size_t)(c0 + 2) * 4);
    float4 w3 = *(const float4*)(cw + (size_t)(c0 + 3) * 4);
    float4 acc = *(const float4*)(cb + c0);
    const float* wp0 = (const float*)&w0;
    const float* wp1 = (const float*)&w1;
    const float* wp2 = (const float*)&w2;
    const float* wp3 = (const float*)&w3;
#pragma unroll
    for (int k = 0; k < 4; ++k) {
        int lp = l - 3 + k;
        if (lp >= 0) {
            ushort4 xv = *(const ushort4*)(xzb + (size_t)(m - l + lp) * 2048 + c0);
            acc.x = fmaf(wp0[k], b2f(xv.x), acc.x);
            acc.y = fmaf(wp1[k], b2f(xv.y), acc.y);
            acc.z = fmaf(wp2[k], b2f(xv.z), acc.z);
            acc.w = fmaf(wp3[k], b2f(xv.w), acc.w);
        }
    }
    ushort4 o = { f2b(silu(acc.x)), f2b(silu(acc.y)), f2b(silu(acc.z)), f2b(silu(acc.w)) };
    *(ushort4*)(xcb + (size_t)m * 1024 + c0) = o;
}

// ---------------------------------------------------------------------------
// Chunked selective scan.  L=1024 split into NC=32 chunks of CL=32.
// Thread = (b, d, chunk), 16 states in registers.  dt/u staged in LDS.
// Summaries COMPRESSED: phase0 stores packed uint32 (bf16 a | bf16 h << 16);
// carry writes compact bf16 h_init; phase1 reads bf16 h_init.
// Power fast path: A[s]=(s+1)*A[0] -> a_s = a1^(s+1) (guarded, exact fallback).
// Block = 256 threads = 256 consecutive d; grid (4 dgrp, 8 b, NC chunk).
constexpr int SCAN_NC = 32;
constexpr int SCAN_CL = 32;

template <int PHASE>
__global__ __launch_bounds__(256) void k_scan_chunk(
        const unsigned short* __restrict__ dtb, const unsigned short* __restrict__ xcb,
        const float* __restrict__ xdbl, const unsigned short* __restrict__ xzb,
        const float* __restrict__ Alog, const float* __restrict__ Dp,
        unsigned int* __restrict__ sum, const unsigned short* __restrict__ hinit,
        unsigned short* __restrict__ ybf) {
    constexpr int CL = SCAN_CL;
    const int tid = threadIdx.x;
    const int d0 = blockIdx.x * 256;
    const int d = d0 + tid;
    const int b = blockIdx.y, c = blockIdx.z;
    const size_t mbase = (size_t)b * 1024 + (size_t)c * CL;

    // bulk-stage chunk inputs into LDS (coalesced 16B chunks, all in flight):
    //   sBC: B/C slice of xdbl; sdt/su: this block's dt/u [CL][256] bf16.
    __shared__ float sBC[CL][32];
    __shared__ unsigned short sdt[CL][256];
    __shared__ unsigned short su[CL][256];
    {
        int row = tid >> 3, q = tid & 7;   // CL*8 == 256
        *(float4*)&sBC[row][q * 4] =
            *(const float4*)(xdbl + (mbase + row) * 64 + 32 + q * 4);
    }
    for (int i = tid; i < CL * 32; i += 256) {       // 32 rows x 32 16B-chunks
        int row = i >> 5, q = i & 31;
        const size_t g = (mbase + row) * 1024 + d0 + q * 8;
        *(int4*)&sdt[row][q * 8] = *(const int4*)(dtb + g);
        *(int4*)&su[row][q * 8]  = *(const int4*)(xcb + g);
    }
    __syncthreads();

    constexpr float LOG2E = 1.4426950408889634f;
    float A2[16], h[16];
#pragma unroll
    for (int s = 0; s < 16; ++s) A2[s] = -expf(Alog[d * 16 + s]) * LOG2E;

    // integer-ratio check: A2[s] == (s+1)*A2[0] to ~1e-5 rel
    bool powok = true;
#pragma unroll
    for (int s = 1; s < 16; ++s)
        powok = powok && (fabsf(A2[s] - (float)(s + 1) * A2[0]) <=
                          1e-5f * fabsf(A2[s]));

    const size_t sumbase = ((size_t)(b * SCAN_NC + c) << 14) + d * 16;
    if (PHASE == 0) {
#pragma unroll
        for (int s = 0; s < 16; ++s) h[s] = 0.f;
    } else {
#pragma unroll
        for (int s = 0; s < 16; s += 8) {
            bf16x8 hv = *(const bf16x8*)(hinit + sumbase + s);
#pragma unroll
            for (int j = 0; j < 8; ++j) h[s + j] = b2f((unsigned short)hv[j]);
        }
    }
    float dtsum = 0.f;
    const float Dv = (PHASE == 1) ? Dp[d] : 0.f;

    // z prefetch one step ahead (phase 1 only)
    float zv_n = 0.f;
    if (PHASE == 1) zv_n = b2f(xzb[mbase * 2048 + 1024 + d]);

#pragma unroll 2
    for (int l = 0; l < CL; ++l) {
        const size_t m = mbase + l;
        const float dtv_c = b2f(sdt[l][tid]);
        const float uv_c  = b2f(su[l][tid]);
        float zv;
        if (PHASE == 1) {
            zv = zv_n;
            if (l + 1 < CL) zv_n = b2f(xzb[(m + 1) * 2048 + 1024 + d]);
        }
        const float dtu = dtv_c * uv_c;
        if (PHASE == 0) dtsum += dtv_c;
        float Bv[16], Cv[16];
#pragma unroll
        for (int q = 0; q < 4; ++q) {
            *(float4*)&Bv[q * 4] = *(const float4*)&sBC[l][q * 4];
            if (PHASE == 1)
                *(float4*)&Cv[q * 4] = *(const float4*)&sBC[l][16 + q * 4];
        }
        float p = 0.f;
        if (powok) {
            const float a1 = fexp2(dtv_c * A2[0]);
            float a = a1;
#pragma unroll
            for (int s = 0; s < 16; ++s) {
                h[s] = fmaf(a, h[s], dtu * Bv[s]);
                if (PHASE == 1) p = fmaf(h[s], Cv[s], p);
                a *= a1;
            }
        } else {
#pragma unroll
            for (int s = 0; s < 16; ++s) {
                float a = fexp2(dtv_c * A2[s]);
                h[s] = fmaf(a, h[s], dtu * Bv[s]);
                if (PHASE == 1) p = fmaf(h[s], Cv[s], p);
            }
        }
        if (PHASE == 1) {
            ybf[m * 1024 + d] = f2b((p + Dv * uv_c) * silu(zv));
        }
    }
    if (PHASE == 0) {
        float aprod[16];
        if (powok) {
            const float ap1 = fexp2(A2[0] * dtsum);
            float a = ap1;
#pragma unroll
            for (int s = 0; s < 16; ++s) { aprod[s] = a; a *= ap1; }
        } else {
#pragma unroll
            for (int s = 0; s < 16; ++s) aprod[s] = fexp2(A2[s] * dtsum);
        }
        unsigned int pk[16];
#pragma unroll
        for (int s = 0; s < 16; ++s)
            pk[s] = (unsigned int)f2b(aprod[s]) | ((unsigned int)f2b(h[s]) << 16);
#pragma unroll
        for (int s = 0; s < 16; s += 4)
            *(uint4*)(sum + sumbase + s) = *(const uint4*)&pk[s];
    }
}

// carry scan over packed chunk summaries; writes compact bf16 h_init.
__global__ __launch_bounds__(256) void k_scan_carry(const unsigned int* __restrict__ sum,
                                                    unsigned short* __restrict__ hinit) {
    int i = blockIdx.x * 256 + threadIdx.x;   // (b, d*16+s)
    int b = i >> 14, ds = i & 16383;
    float h = 0.f;
    for (int c = 0; c < SCAN_NC; ++c) {
        size_t idx = ((size_t)(b * SCAN_NC + c) << 14) + ds;
        unsigned int u = sum[idx];
        float a = b2f((unsigned short)(u & 0xffffu));
        float f = b2f((unsigned short)(u >> 16));
        hinit[idx] = f2b(h);
        h = fmaf(a, h, f);
    }
}

// ---------------------------------------------------------------------------
extern "C" void kernel_launch(void* const* d_in, const int* in_sizes, int n_in,
                              void* d_out, int out_size, void* d_ws, size_t ws_size,
                              hipStream_t stream) {
    const float* x         = (const float*)d_in[0];
    const float* skip      = (const float*)d_in[1];
    const float* up_w      = (const float*)d_in[2];
    const float* up_b      = (const float*)d_in[3];
    const float* merge_w   = (const float*)d_in[4];
    const float* merge_b   = (const float*)d_in[5];
    const float* ln_w      = (const float*)d_in[6];
    const float* ln_b      = (const float*)d_in[7];
    const float* in_proj_w = (const float*)d_in[8];
    const float* conv_w    = (const float*)d_in[9];
    const float* conv_b    = (const float*)d_in[10];
    const float* x_proj_w  = (const float*)d_in[11];
    const float* dt_proj_w = (const float*)d_in[12];
    const float* dt_proj_b = (const float*)d_in[13];
    const float* A_log     = (const float*)d_in[14];
    const float* D_param   = (const float*)d_in[15];
    const float* out_proj_w= (const float*)d_in[16];
    float* out = (float*)d_out;

    char* ws = (char*)d_ws;
    size_t off = 0;
    auto alloc = [&](size_t bytes) { size_t r = off; off += (bytes + 255) & ~(size_t)255; return r; };

    // persistent
    unsigned short* upT  = (unsigned short*)(ws + alloc(2048ull * 512 * 2));
    unsigned short* mw   = (unsigned short*)(ws + alloc(512ull * 1024 * 2));
    unsigned short* ipw  = (unsigned short*)(ws + alloc(2ull * 2048 * 512 * 2));
    unsigned short* xpw  = (unsigned short*)(ws + alloc(2ull * 64 * 1024 * 2));
    unsigned short* opw  = (unsigned short*)(ws + alloc(2ull * 512 * 1024 * 2));
    unsigned short* xbf  = (unsigned short*)(ws + alloc(4096ull * 512 * 2));
    unsigned short* ubf  = (unsigned short*)(ws + alloc(8192ull * 512 * 2));
    // per-layer arena (stage-1 buffers aliased in)
    unsigned short* xzbf  = (unsigned short*)(ws + alloc(8192ull * 2048 * 2));
    unsigned short* xcbf  = (unsigned short*)(ws + alloc(8192ull * 1024 * 2));
    float*          xdbl  = (float*)(ws + alloc(8192ull * 64 * 4));
    unsigned short* dtbf  = (unsigned short*)(ws + alloc(8192ull * 1024 * 2));
    unsigned short* ybf   = (unsigned short*)(ws + alloc(8192ull * 1024 * 2));
    unsigned int*   scan_sum   = (unsigned int*)(ws + alloc((size_t)SCAN_NC * 8 * 16384 * 4));
    unsigned short* scan_hinit = (unsigned short*)(ws + alloc((size_t)SCAN_NC * 8 * 16384 * 2));
    unsigned short* dtpA  = (unsigned short*)(ws + alloc(8192ull * 128 * 2));
    unsigned short* dtpB  = (unsigned short*)(ws + alloc(2048ull * 128 * 2));
    float*          P      = (float*)xzbf;          // 32MB == 32MB, dead before in_proj
    unsigned short* catbf  = dtbf;                  // 16MB == 16MB, dead before dt GEMM
    float*          merged = (float*)xcbf;          // 16MB == 16MB, dead before conv

    // fused weight prep (cvt x/merge/in_proj/x_proj/out_proj + dtpackB both layers)
    k_prep<<<6017, 256, 0, stream>>>(x, merge_w, in_proj_w, x_proj_w, out_proj_w,
                                     dt_proj_w, xbf, mw, ipw, xpw, opw, dtpB);
    k_upT<<<dim3(16, 16, 4), dim3(32, 32), 0, stream>>>(up_w, upT);

    // stage 1: transposed-conv as GEMM, assemble cat, merge GEMM, LN
    k_gemm<128, 128, 0><<<dim3(16, 32), 256, 0, stream>>>(xbf, upT, P, nullptr, nullptr,
                                                          4096, 2048, 512);
    k_assemble<<<32768, 256, 0, stream>>>(P, skip, up_b, catbf);
    k_gemm<128, 128, 0><<<dim3(4, 64), 256, 0, stream>>>(catbf, mw, merged, nullptr, merge_b,
                                                         8192, 512, 1024);
    k_ln<<<2048, 256, 0, stream>>>(merged, ln_w, ln_b, ubf);

    // two mamba layers
    for (int li = 0; li < 2; ++li) {
        k_gemm<128, 128, 1><<<dim3(16, 64), 256, 0, stream>>>(ubf, ipw + (size_t)li * 2048 * 512,
                                                              nullptr, xzbf, nullptr, 8192, 2048, 512);
        k_conv<<<8192, 256, 0, stream>>>(xzbf, conv_w + li * 4096, conv_b + li * 1024, xcbf);
        // x_proj GEMM with fused dtpackA epilogue (cols<32 -> split-bf16 operand)
        k_gemm<64, 64, 4><<<dim3(1, 128), 256, 0, stream>>>(xcbf, xpw + (size_t)li * 64 * 1024,
                                                            xdbl, dtpA, nullptr, 8192, 64, 1024);
        // dt GEMM: exact split-bf16 (K=128) + fused hw-softplus -> bf16
        k_gemm<128, 64, 3><<<dim3(16, 64), 256, 0, stream>>>(dtpA, dtpB + (size_t)li * 1024 * 128,
                                                             nullptr, dtbf,
                                                             dt_proj_b + (size_t)li * 1024,
                                                             8192, 1024, 128);
        const float* Al = A_log + (size_t)li * 1024 * 16;
        const float* Dl = D_param + (size_t)li * 1024;
        k_scan_chunk<0><<<dim3(4, 8, SCAN_NC), 256, 0, stream>>>(
            dtbf, xcbf, xdbl, xzbf, Al, Dl, scan_sum, scan_hinit, ybf);
        k_scan_carry<<<512, 256, 0, stream>>>(scan_sum, scan_hinit);
        k_scan_chunk<1><<<dim3(4, 8, SCAN_NC), 256, 0, stream>>>(
            dtbf, xcbf, xdbl, xzbf, Al, Dl, scan_sum, scan_hinit, ybf);
        if (li == 0)
            k_gemm<128, 128, 1><<<dim3(4, 64), 256, 0, stream>>>(ybf, opw, nullptr, ubf, nullptr,
                                                                 8192, 512, 1024);
        else
            k_gemm<128, 128, 0><<<dim3(4, 64), 256, 0, stream>>>(ybf, opw + (size_t)512 * 1024,
                                                                 out, nullptr, nullptr, 8192, 512, 1024);
    }
}

// Round 24
// 404.393 us; speedup vs baseline: 1.1442x; 1.0098x over previous
//
#include <hip/hip_runtime.h>

#define DEV __device__ __forceinline__

typedef short  bf16x8 __attribute__((ext_vector_type(8)));
typedef float  f32x4  __attribute__((ext_vector_type(4)));

DEV unsigned short f2b(float f) {
    unsigned int u = __float_as_uint(f);
    u += 0x7fffu + ((u >> 16) & 1u);
    return (unsigned short)(u >> 16);
}
DEV float b2f(unsigned short h) { return __uint_as_float((unsigned int)h << 16); }
DEV float silu(float x) { return x / (1.f + __expf(-x)); }
DEV float fexp2(float x) { return __builtin_amdgcn_exp2f(x); }   // raw v_exp_f32
DEV float flog2(float x) { return __builtin_amdgcn_logf(x); }    // raw v_log_f32

// async global->LDS, 16B per lane: HW writes lane l at ldsbase + l*16
typedef const __attribute__((address_space(1))) unsigned int GU32;
typedef __attribute__((address_space(3))) unsigned int LU32;
DEV void gload16(const unsigned short* g, unsigned short* l) {
    __builtin_amdgcn_global_load_lds((GU32*)g, (LU32*)l, 16, 0, 0);
}

// ---------------------------------------------------------------------------
// fused prep: weight f32->bf16 conversions + dt_proj_w split-bf16 packing +
// scan A2 table (-exp(A_log)*log2e) with integer-power flag.
__global__ __launch_bounds__(256) void k_prep(
        const float* __restrict__ x, const float* __restrict__ merge_w,
        const float* __restrict__ in_proj_w, const float* __restrict__ x_proj_w,
        const float* __restrict__ out_proj_w, const float* __restrict__ dt_proj_w,
        const float* __restrict__ A_log,
        unsigned short* __restrict__ xbf, unsigned short* __restrict__ mw,
        unsigned short* __restrict__ ipw, unsigned short* __restrict__ xpw,
        unsigned short* __restrict__ opw, unsigned short* __restrict__ dtpB,
        float* __restrict__ A2tab, int* __restrict__ powflag) {
    size_t i = (size_t)blockIdx.x * 256 + threadIdx.x;
    const size_t n0 = 524288;           // x: 4096*512/4
    const size_t n1 = n0 + 131072;      // merge_w: 512*1024/4
    const size_t n2 = n1 + 524288;      // in_proj: 2*2048*512/4
    const size_t n3 = n2 + 32768;       // x_proj: 2*64*1024/4
    const size_t n4 = n3 + 262144;      // out_proj: 2*512*1024/4
    const size_t n5 = n4 + 65536;       // dtpackB: 2*1024*32 scalars
    const size_t n6 = n5 + 2048;        // A2 table: one thread per d (2 layers)
    if (i < n4) {
        const float* s; unsigned short* d; size_t j;
        if (i < n0)      { s = x;          d = xbf; j = i; }
        else if (i < n1) { s = merge_w;    d = mw;  j = i - n0; }
        else if (i < n2) { s = in_proj_w;  d = ipw; j = i - n1; }
        else if (i < n3) { s = x_proj_w;   d = xpw; j = i - n2; }
        else             { s = out_proj_w; d = opw; j = i - n3; }
        float4 v = *(const float4*)(s + j * 4);
        ushort4 o = { f2b(v.x), f2b(v.y), f2b(v.z), f2b(v.w) };
        *(ushort4*)(d + j * 4) = o;
    } else if (i < n5) {
        size_t j = i - n4;              // (li*1024+d)*32 + r
        int r = (int)(j & 31);
        size_t dg = j >> 5;             // global d in [0, 2048)
        float xw = dt_proj_w[dg * 32 + r];
        unsigned short wh = f2b(xw);
        unsigned short wl = f2b(xw - b2f(wh));
        size_t base = dg * 128;
        dtpB[base + r]      = wh;
        dtpB[base + 32 + r] = wl;
        dtpB[base + 64 + r] = wl;
        dtpB[base + 96 + r] = wh;
    } else if (i < n6) {
        size_t dg = i - n5;             // [0, 2048)
        constexpr float LOG2E = 1.4426950408889634f;
        float a2[16];
#pragma unroll
        for (int s = 0; s < 16; ++s)
            a2[s] = -expf(A_log[dg * 16 + s]) * LOG2E;
        bool ok = true;
#pragma unroll
        for (int s = 1; s < 16; ++s)
            ok = ok && (fabsf(a2[s] - (float)(s + 1) * a2[0]) <= 1e-5f * fabsf(a2[s]));
#pragma unroll
        for (int s = 0; s < 16; s += 4)
            *(f32x4*)(A2tab + dg * 16 + s) = *(const f32x4*)&a2[s];
        powflag[dg] = ok ? 1 : 0;
    }
}

// up_w (512 x 512 x 4) [i,o,k] -> upT[(k*512+o)*512 + i] bf16
__global__ void k_upT(const float* __restrict__ up_w, unsigned short* __restrict__ upT) {
    __shared__ float t[32][33];
    int tx = threadIdx.x, ty = threadIdx.y;
    int o0 = blockIdx.x * 32, i0 = blockIdx.y * 32, kz = blockIdx.z;
    t[ty][tx] = up_w[(size_t)(i0 + ty) * 2048 + (o0 + tx) * 4 + kz];
    __syncthreads();
    upT[(size_t)(kz * 512 + o0 + ty) * 512 + i0 + tx] = f2b(t[tx][ty]);
}

// ---------------------------------------------------------------------------
// bf16 MFMA GEMM, NT: C[m,n] = sum_k A[m,k]*B[n,k].  BK=64, 4 waves,
// global_load_lds staging with T2 XOR-swizzle (rule #21: linear LDS dest +
// inverse-swizzled GLOBAL source + swizzled READ).
// XCD-aware block swizzle (T1): contiguous tile chunks per XCD for L2 reuse.
// Tiles: (BM,BN) in {(128,128),(128,64),(64,64)}.
// OUTMODE 0: f32 out, 1: bf16 out, 2: softplus->f32, 3: softplus->bf16,
//         4: f32 out + dtpackA for cols<32 (split-bf16 K=128 operand).
template <int BM, int BN, int OUTMODE>
__global__ __launch_bounds__(256) void k_gemm(const unsigned short* __restrict__ A,
                                              const unsigned short* __restrict__ B,
                                              float* __restrict__ Cf,
                                              unsigned short* __restrict__ Cb,
                                              const float* __restrict__ bias,
                                              int M, int N, int K) {
    constexpr int BK = 64;
    constexpr int WM = (BN == 128) ? 64 : 32;
    constexpr int WN = (BM == 64 && BN == 64) ? 32 : 64;
    constexpr int MI = WM / 16, NI = WN / 16;
    __shared__ unsigned short As[BM * BK];
    __shared__ unsigned short Bs[BN * BK];
    const int tid = threadIdx.x;
    const int wid = tid >> 6, lane = tid & 63;

    // XCD swizzle: hw bids round-robin XCDs; map same-XCD bids to contiguous tiles
    int bid = blockIdx.y * gridDim.x + blockIdx.x;
    const int nwg = gridDim.x * gridDim.y;
    if ((nwg & 7) == 0) {
        int cpx = nwg >> 3;
        bid = (bid & 7) * cpx + (bid >> 3);
    }
    const int bx = bid % gridDim.x, by = bid / gridDim.x;
    const int m0 = by * BM, n0 = bx * BN;

    int wr, wc;
    if (BN == 128)      { wr = wid >> 1; wc = wid & 1; }
    else if (BM == 128) { wr = wid;      wc = 0;       }
    else                { wr = wid & 1;  wc = wid >> 1; }
    const int wm0 = wr * WM, wn0 = wc * WN;
    const int fr = lane & 15, fh = lane >> 4;

    // staging (BK=64): one gload16 covers 8 rows; lane l -> row (l>>3).
    // Global source col chunk pre-swizzled: chunk = (l&7) ^ (l>>3), because
    // staged rows step by 32 so (row & 7) == (l>>3) for this lane always.
    const int srow = lane >> 3;
    const int scol = (((lane & 7) ^ srow)) * 8;
    const unsigned short* Ag = A + (size_t)(m0 + wid * 8 + srow) * K + scol;
    const unsigned short* Bg = B + (size_t)(n0 + wid * 8 + srow) * K + scol;
    unsigned short* AsB = &As[wid * 8 * BK];
    unsigned short* BsB = &Bs[wid * 8 * BK];

    f32x4 acc[MI][NI];
#pragma unroll
    for (int i = 0; i < MI; ++i)
#pragma unroll
        for (int j = 0; j < NI; ++j) acc[i][j] = (f32x4){0.f, 0.f, 0.f, 0.f};

    const int frx = fr & 7;   // read-side XOR factor (row & 7)
    for (int k0 = 0; k0 < K; k0 += BK) {
#pragma unroll
        for (int i = 0; i < BM / 32; ++i)
            gload16(Ag + (size_t)(i * 32) * K + k0, AsB + i * 32 * BK);
#pragma unroll
        for (int i = 0; i < BN / 32; ++i)
            gload16(Bg + (size_t)(i * 32) * K + k0, BsB + i * 32 * BK);
        __syncthreads();
#pragma unroll
        for (int kk = 0; kk < BK; kk += 32) {
            bf16x8 av[MI], bv[NI];
#pragma unroll
            for (int mi = 0; mi < MI; ++mi)
                av[mi] = *(const bf16x8*)(&As[(wm0 + mi * 16 + fr) * BK +
                                              ((((kk >> 3) + fh) ^ frx) << 3)]);
#pragma unroll
            for (int ni = 0; ni < NI; ++ni)
                bv[ni] = *(const bf16x8*)(&Bs[(wn0 + ni * 16 + fr) * BK +
                                              ((((kk >> 3) + fh) ^ frx) << 3)]);
#pragma unroll
            for (int mi = 0; mi < MI; ++mi)
#pragma unroll
                for (int ni = 0; ni < NI; ++ni)
                    acc[mi][ni] = __builtin_amdgcn_mfma_f32_16x16x32_bf16(av[mi], bv[ni],
                                                                          acc[mi][ni], 0, 0, 0);
        }
        __syncthreads();
    }
    constexpr float LOG2E = 1.4426950408889634f;
    constexpr float LN2   = 0.6931471805599453f;
#pragma unroll
    for (int mi = 0; mi < MI; ++mi) {
#pragma unroll
        for (int ni = 0; ni < NI; ++ni) {
            int col = n0 + wn0 + ni * 16 + fr;
            float bb = bias ? bias[col] : 0.f;
#pragma unroll
            for (int j = 0; j < 4; ++j) {
                int row = m0 + wm0 + mi * 16 + fh * 4 + j;
                float v = acc[mi][ni][j] + bb;
                if (OUTMODE == 0)      Cf[(size_t)row * N + col] = v;
                else if (OUTMODE == 1) Cb[(size_t)row * N + col] = f2b(v);
                else if (OUTMODE == 4) {
                    Cf[(size_t)row * N + col] = v;
                    if (col < 32) {
                        unsigned short xh = f2b(v);
                        unsigned short xl = f2b(v - b2f(xh));
                        size_t base = (size_t)row * 128;
                        Cb[base + col]      = xh;
                        Cb[base + 32 + col] = xl;
                        Cb[base + 64 + col] = xh;
                        Cb[base + 96 + col] = xl;
                    }
                } else {
                    float sp = (v > 20.f) ? v : flog2(1.f + fexp2(v * LOG2E)) * LN2;
                    if (OUTMODE == 2) Cf[(size_t)row * N + col] = sp;
                    else              Cb[(size_t)row * N + col] = f2b(sp);
                }
            }
        }
    }
}

// ---------------------------------------------------------------------------
// assemble cat row-major (8192 x 1024) bf16: [0,512)=xu from P(bf16), rest=skip
__global__ __launch_bounds__(256) void k_assemble(const unsigned short* __restrict__ P,
                                                  const float* __restrict__ skip,
                                                  const float* __restrict__ up_b,
                                                  unsigned short* __restrict__ catbf) {
    int bx = blockIdx.x;
    int m = bx >> 2;
    int c = (bx & 3) * 256 + threadIdx.x;
    int b = m >> 10, t = m & 1023, j = t >> 1;
    float v;
    if (c < 512) {
        size_t rb = (size_t)((b << 9) + j) * 2048;
        if (t & 1) {                       // odd t: k=2 @ j, k=0 @ j+1
            v = b2f(P[rb + 1024 + c]);
            if (j + 1 < 512) v += b2f(P[rb + 2048 + c]);
        } else {                           // even t: k=3 @ j-1, k=1 @ j
            v = b2f(P[rb + 512 + c]);
            if (j >= 1) v += b2f(P[rb - 2048 + 1536 + c]);
        }
        v += up_b[c];
    } else {
        v = skip[(size_t)m * 512 + (c - 512)];
    }
    catbf[(size_t)m * 1024 + c] = f2b(v);
}

// LayerNorm over 512, 4 rows per 256-block, writes bf16
__global__ __launch_bounds__(256) void k_ln(const float* __restrict__ merged,
                                            const float* __restrict__ w,
                                            const float* __restrict__ bvec,
                                            unsigned short* __restrict__ outb) {
    int row = blockIdx.x * 4 + (threadIdx.x >> 6);
    int lane = threadIdx.x & 63;
    const float* r = merged + (size_t)row * 512 + lane * 8;
    float4 v1 = *(const float4*)r;
    float4 v2 = *(const float4*)(r + 4);
    float xv[8] = {v1.x, v1.y, v1.z, v1.w, v2.x, v2.y, v2.z, v2.w};
    float s = 0.f, ss = 0.f;
#pragma unroll
    for (int e = 0; e < 8; ++e) { s += xv[e]; ss += xv[e] * xv[e]; }
#pragma unroll
    for (int m = 1; m < 64; m <<= 1) { s += __shfl_xor(s, m, 64); ss += __shfl_xor(ss, m, 64); }
    float mean = s * (1.f / 512.f);
    float var = ss * (1.f / 512.f) - mean * mean;
    float inv = rsqrtf(var + 1e-5f);
    unsigned short o8[8];
#pragma unroll
    for (int e = 0; e < 8; ++e) {
        int c = lane * 8 + e;
        o8[e] = f2b((xv[e] - mean) * inv * w[c] + bvec[c]);
    }
    *(int4*)(outb + (size_t)row * 512 + lane * 8) = *(const int4*)o8;
}

// causal depthwise conv K=4 + bias + silu; 4 channels/thread, bf16 in/out
__global__ __launch_bounds__(256) void k_conv(const unsigned short* __restrict__ xzb,
                                              const float* __restrict__ cw,
                                              const float* __restrict__ cb,
                                              unsigned short* __restrict__ xcb) {
    int i = blockIdx.x * 256 + threadIdx.x;   // 2.1M threads
    int m = i >> 8;
    int c0 = (i & 255) * 4;
    int l = m & 1023;
    float4 w0 = *(const float4*)(cw + (size_t)(c0 + 0) * 4);
    float4 w1 = *(const float4*)(cw + (size_t)(c0 + 1) * 4);
    float4 w2 = *(const float4*)(cw + (size_t)(c0 + 2) * 4);
    float4 w3 = *(const float4*)(cw + (size_t)(c0 + 3) * 4);
    float4 acc = *(const float4*)(cb + c0);
    const float* wp0 = (const float*)&w0;
    const float* wp1 = (const float*)&w1;
    const float* wp2 = (const float*)&w2;
    const float* wp3 = (const float*)&w3;
#pragma unroll
    for (int k = 0; k < 4; ++k) {
        int lp = l - 3 + k;
        if (lp >= 0) {
            ushort4 xv = *(const ushort4*)(xzb + (size_t)(m - l + lp) * 2048 + c0);
            acc.x = fmaf(wp0[k], b2f(xv.x), acc.x);
            acc.y = fmaf(wp1[k], b2f(xv.y), acc.y);
            acc.z = fmaf(wp2[k], b2f(xv.z), acc.z);
            acc.w = fmaf(wp3[k], b2f(xv.w), acc.w);
        }
    }
    ushort4 o = { f2b(silu(acc.x)), f2b(silu(acc.y)), f2b(silu(acc.z)), f2b(silu(acc.w)) };
    *(ushort4*)(xcb + (size_t)m * 1024 + c0) = o;
}

// ---------------------------------------------------------------------------
// Chunked selective scan.  L=1024 split into NC=32 chunks of CL=32.
// Thread = (b, d, chunk), 16 states in registers.  dt/u staged in LDS;
// A2 row + power flag loaded from precomputed table (k_prep).
// Summaries COMPRESSED: phase0 stores packed uint32 (bf16 a | bf16 h << 16);
// carry writes compact bf16 h_init; phase1 reads bf16 h_init.
constexpr int SCAN_NC = 32;
constexpr int SCAN_CL = 32;

template <int PHASE>
__global__ __launch_bounds__(256) void k_scan_chunk(
        const unsigned short* __restrict__ dtb, const unsigned short* __restrict__ xcb,
        const float* __restrict__ xdbl, const unsigned short* __restrict__ xzb,
        const float* __restrict__ A2tab, const int* __restrict__ powflag,
        const float* __restrict__ Dp,
        unsigned int* __restrict__ sum, const unsigned short* __restrict__ hinit,
        unsigned short* __restrict__ ybf) {
    constexpr int CL = SCAN_CL;
    const int tid = threadIdx.x;
    const int d0 = blockIdx.x * 256;
    const int d = d0 + tid;
    const int b = blockIdx.y, c = blockIdx.z;
    const size_t mbase = (size_t)b * 1024 + (size_t)c * CL;

    // bulk-stage chunk inputs into LDS (coalesced 16B chunks, all in flight):
    //   sBC: B/C slice of xdbl; sdt/su: this block's dt/u [CL][256] bf16.
    __shared__ float sBC[CL][32];
    __shared__ unsigned short sdt[CL][256];
    __shared__ unsigned short su[CL][256];
    {
        int row = tid >> 3, q = tid & 7;   // CL*8 == 256
        *(float4*)&sBC[row][q * 4] =
            *(const float4*)(xdbl + (mbase + row) * 64 + 32 + q * 4);
    }
    for (int i = tid; i < CL * 32; i += 256) {       // 32 rows x 32 16B-chunks
        int row = i >> 5, q = i & 31;
        const size_t g = (mbase + row) * 1024 + d0 + q * 8;
        *(int4*)&sdt[row][q * 8] = *(const int4*)(dtb + g);
        *(int4*)&su[row][q * 8]  = *(const int4*)(xcb + g);
    }
    __syncthreads();

    float A2[16], h[16];
#pragma unroll
    for (int s = 0; s < 16; s += 4)
        *(f32x4*)&A2[s] = *(const f32x4*)(A2tab + (size_t)d * 16 + s);
    const bool powok = powflag[d] != 0;

    const size_t sumbase = ((size_t)(b * SCAN_NC + c) << 14) + d * 16;
    if (PHASE == 0) {
#pragma unroll
        for (int s = 0; s < 16; ++s) h[s] = 0.f;
    } else {
#pragma unroll
        for (int s = 0; s < 16; s += 8) {
            bf16x8 hv = *(const bf16x8*)(hinit + sumbase + s);
#pragma unroll
            for (int j = 0; j < 8; ++j) h[s + j] = b2f((unsigned short)hv[j]);
        }
    }
    float dtsum = 0.f;
    const float Dv = (PHASE == 1) ? Dp[d] : 0.f;

    // z prefetch one step ahead (phase 1 only)
    float zv_n = 0.f;
    if (PHASE == 1) zv_n = b2f(xzb[mbase * 2048 + 1024 + d]);

#pragma unroll 2
    for (int l = 0; l < CL; ++l) {
        const size_t m = mbase + l;
        const float dtv_c = b2f(sdt[l][tid]);
        const float uv_c  = b2f(su[l][tid]);
        float zv;
        if (PHASE == 1) {
            zv = zv_n;
            if (l + 1 < CL) zv_n = b2f(xzb[(m + 1) * 2048 + 1024 + d]);
        }
        const float dtu = dtv_c * uv_c;
        if (PHASE == 0) dtsum += dtv_c;
        float Bv[16], Cv[16];
#pragma unroll
        for (int q = 0; q < 4; ++q) {
            *(float4*)&Bv[q * 4] = *(const float4*)&sBC[l][q * 4];
            if (PHASE == 1)
                *(float4*)&Cv[q * 4] = *(const float4*)&sBC[l][16 + q * 4];
        }
        float p = 0.f;
        if (powok) {
            const float a1 = fexp2(dtv_c * A2[0]);
            float a = a1;
#pragma unroll
            for (int s = 0; s < 16; ++s) {
                h[s] = fmaf(a, h[s], dtu * Bv[s]);
                if (PHASE == 1) p = fmaf(h[s], Cv[s], p);
                a *= a1;
            }
        } else {
#pragma unroll
            for (int s = 0; s < 16; ++s) {
                float a = fexp2(dtv_c * A2[s]);
                h[s] = fmaf(a, h[s], dtu * Bv[s]);
                if (PHASE == 1) p = fmaf(h[s], Cv[s], p);
            }
        }
        if (PHASE == 1) {
            ybf[m * 1024 + d] = f2b((p + Dv * uv_c) * silu(zv));
        }
    }
    if (PHASE == 0) {
        float aprod[16];
        if (powok) {
            const float ap1 = fexp2(A2[0] * dtsum);
            float a = ap1;
#pragma unroll
            for (int s = 0; s < 16; ++s) { aprod[s] = a; a *= ap1; }
        } else {
#pragma unroll
            for (int s = 0; s < 16; ++s) aprod[s] = fexp2(A2[s] * dtsum);
        }
        unsigned int pk[16];
#pragma unroll
        for (int s = 0; s < 16; ++s)
            pk[s] = (unsigned int)f2b(aprod[s]) | ((unsigned int)f2b(h[s]) << 16);
#pragma unroll
        for (int s = 0; s < 16; s += 4)
            *(uint4*)(sum + sumbase + s) = *(const uint4*)&pk[s];
    }
}

// carry scan over packed chunk summaries; writes compact bf16 h_init.
__global__ __launch_bounds__(256) void k_scan_carry(const unsigned int* __restrict__ sum,
                                                    unsigned short* __restrict__ hinit) {
    int i = blockIdx.x * 256 + threadIdx.x;   // (b, d*16+s)
    int b = i >> 14, ds = i & 16383;
    float h = 0.f;
    for (int c = 0; c < SCAN_NC; ++c) {
        size_t idx = ((size_t)(b * SCAN_NC + c) << 14) + ds;
        unsigned int u = sum[idx];
        float a = b2f((unsigned short)(u & 0xffffu));
        float f = b2f((unsigned short)(u >> 16));
        hinit[idx] = f2b(h);
        h = fmaf(a, h, f);
    }
}

// ---------------------------------------------------------------------------
extern "C" void kernel_launch(void* const* d_in, const int* in_sizes, int n_in,
                              void* d_out, int out_size, void* d_ws, size_t ws_size,
                              hipStream_t stream) {
    const float* x         = (const float*)d_in[0];
    const float* skip      = (const float*)d_in[1];
    const float* up_w      = (const float*)d_in[2];
    const float* up_b      = (const float*)d_in[3];
    const float* merge_w   = (const float*)d_in[4];
    const float* merge_b   = (const float*)d_in[5];
    const float* ln_w      = (const float*)d_in[6];
    const float* ln_b      = (const float*)d_in[7];
    const float* in_proj_w = (const float*)d_in[8];
    const float* conv_w    = (const float*)d_in[9];
    const float* conv_b    = (const float*)d_in[10];
    const float* x_proj_w  = (const float*)d_in[11];
    const float* dt_proj_w = (const float*)d_in[12];
    const float* dt_proj_b = (const float*)d_in[13];
    const float* A_log     = (const float*)d_in[14];
    const float* D_param   = (const float*)d_in[15];
    const float* out_proj_w= (const float*)d_in[16];
    float* out = (float*)d_out;

    char* ws = (char*)d_ws;
    size_t off = 0;
    auto alloc = [&](size_t bytes) { size_t r = off; off += (bytes + 255) & ~(size_t)255; return r; };

    // persistent
    unsigned short* upT  = (unsigned short*)(ws + alloc(2048ull * 512 * 2));
    unsigned short* mw   = (unsigned short*)(ws + alloc(512ull * 1024 * 2));
    unsigned short* ipw  = (unsigned short*)(ws + alloc(2ull * 2048 * 512 * 2));
    unsigned short* xpw  = (unsigned short*)(ws + alloc(2ull * 64 * 1024 * 2));
    unsigned short* opw  = (unsigned short*)(ws + alloc(2ull * 512 * 1024 * 2));
    unsigned short* xbf  = (unsigned short*)(ws + alloc(4096ull * 512 * 2));
    unsigned short* ubf  = (unsigned short*)(ws + alloc(8192ull * 512 * 2));
    float*          A2tab   = (float*)(ws + alloc(2048ull * 16 * 4));
    int*            powflag = (int*)(ws + alloc(2048ull * 4));
    // per-layer arena (stage-1 buffers aliased in)
    unsigned short* xzbf  = (unsigned short*)(ws + alloc(8192ull * 2048 * 2));
    unsigned short* xcbf  = (unsigned short*)(ws + alloc(8192ull * 1024 * 2));
    float*          xdbl  = (float*)(ws + alloc(8192ull * 64 * 4));
    unsigned short* dtbf  = (unsigned short*)(ws + alloc(8192ull * 1024 * 2));
    unsigned short* ybf   = (unsigned short*)(ws + alloc(8192ull * 1024 * 2));
    unsigned int*   scan_sum   = (unsigned int*)(ws + alloc((size_t)SCAN_NC * 8 * 16384 * 4));
    unsigned short* scan_hinit = (unsigned short*)(ws + alloc((size_t)SCAN_NC * 8 * 16384 * 2));
    unsigned short* dtpA  = (unsigned short*)(ws + alloc(8192ull * 128 * 2));
    unsigned short* dtpB  = (unsigned short*)(ws + alloc(2048ull * 128 * 2));
    unsigned short* P      = xzbf;                  // 16MB <= 32MB, dead before in_proj
    unsigned short* catbf  = dtbf;                  // 16MB == 16MB, dead before dt GEMM
    float*          merged = (float*)xcbf;          // 16MB == 16MB, dead before conv

    // fused weight prep (cvts + dtpackB + A2 table, both layers)
    k_prep<<<6024, 256, 0, stream>>>(x, merge_w, in_proj_w, x_proj_w, out_proj_w,
                                     dt_proj_w, A_log, xbf, mw, ipw, xpw, opw, dtpB,
                                     A2tab, powflag);
    k_upT<<<dim3(16, 16, 4), dim3(32, 32), 0, stream>>>(up_w, upT);

    // stage 1: transposed-conv as GEMM (bf16 out), assemble cat, merge GEMM, LN
    k_gemm<128, 128, 1><<<dim3(16, 32), 256, 0, stream>>>(xbf, upT, nullptr, P, nullptr,
                                                          4096, 2048, 512);
    k_assemble<<<32768, 256, 0, stream>>>(P, skip, up_b, catbf);
    k_gemm<128, 128, 0><<<dim3(4, 64), 256, 0, stream>>>(catbf, mw, merged, nullptr, merge_b,
                                                         8192, 512, 1024);
    k_ln<<<2048, 256, 0, stream>>>(merged, ln_w, ln_b, ubf);

    // two mamba layers
    for (int li = 0; li < 2; ++li) {
        k_gemm<128, 128, 1><<<dim3(16, 64), 256, 0, stream>>>(ubf, ipw + (size_t)li * 2048 * 512,
                                                              nullptr, xzbf, nullptr, 8192, 2048, 512);
        k_conv<<<8192, 256, 0, stream>>>(xzbf, conv_w + li * 4096, conv_b + li * 1024, xcbf);
        // x_proj GEMM with fused dtpackA epilogue (cols<32 -> split-bf16 operand)
        k_gemm<64, 64, 4><<<dim3(1, 128), 256, 0, stream>>>(xcbf, xpw + (size_t)li * 64 * 1024,
                                                            xdbl, dtpA, nullptr, 8192, 64, 1024);
        // dt GEMM: exact split-bf16 (K=128) + fused hw-softplus -> bf16
        k_gemm<128, 64, 3><<<dim3(16, 64), 256, 0, stream>>>(dtpA, dtpB + (size_t)li * 1024 * 128,
                                                             nullptr, dtbf,
                                                             dt_proj_b + (size_t)li * 1024,
                                                             8192, 1024, 128);
        const float* A2l = A2tab + (size_t)li * 1024 * 16;
        const int*   pfl = powflag + (size_t)li * 1024;
        const float* Dl  = D_param + (size_t)li * 1024;
        k_scan_chunk<0><<<dim3(4, 8, SCAN_NC), 256, 0, stream>>>(
            dtbf, xcbf, xdbl, xzbf, A2l, pfl, Dl, scan_sum, scan_hinit, ybf);
        k_scan_carry<<<512, 256, 0, stream>>>(scan_sum, scan_hinit);
        k_scan_chunk<1><<<dim3(4, 8, SCAN_NC), 256, 0, stream>>>(
            dtbf, xcbf, xdbl, xzbf, A2l, pfl, Dl, scan_sum, scan_hinit, ybf);
        if (li == 0)
            k_gemm<128, 128, 1><<<dim3(4, 64), 256, 0, stream>>>(ybf, opw, nullptr, ubf, nullptr,
                                                                 8192, 512, 1024);
        else
            k_gemm<128, 128, 0><<<dim3(4, 64), 256, 0, stream>>>(ybf, opw + (size_t)512 * 1024,
                                                                 out, nullptr, nullptr, 8192, 512, 1024);
    }
}